// Round 3
// baseline (2987.938 us; speedup 1.0000x reference)
//
#include <hip/hip_runtime.h>
#include <hip/hip_fp16.h>
#include <math.h>

#define Tt 64
#define Bb 16
#define Nn 256
#define Ww 64
#define Rr 4
#define INd 64
#define OUTd 64
#define IFS 471
#define EPSf 1e-6f

// packed half2 weight layout (output-major: contiguous k2 run per output)
#define W1OFF   0        // 256 outputs x 160 k2
#define W2OFF   40960    // 256 x 128
#define WIFOFF  73728    // 471 x 128
#define WOUTOFF 134016   // 64 x 128
#define WMEMOFF 142208   // 64 x 128
#define WTOT    150400

// link: 256 rows x 129 dwords (258 halfs; 256 used + 2 pad)
#define LROW    129
#define LINKB   (256 * LROW * 4)     // 132096 B
#define SCRB    16384                // 4096 floats / 8192 halfs
#define FIXF    2960
#define SMEM_MAIN (LINKB + SCRB + FIXF * 4)   // 160320 <= 163840
#define SMEM_FB   (SCRB + FIXF * 4)

typedef _Float16 h2v __attribute__((ext_vector_type(2)));
__device__ __forceinline__ float fdot2(__half2 a, __half2 b, float c) {
    return __builtin_amdgcn_fdot2(*(h2v*)&a, *(h2v*)&b, c, false);
}
__device__ __forceinline__ __half2 pkh(float a, float b) {
    auto r = __builtin_amdgcn_cvt_pkrtz(a, b);   // __fp16 ext_vector(2)
    return *(__half2*)&r;
}

__device__ __forceinline__ float sigm(float x) { return 1.f / (1.f + expf(-x)); }
__device__ __forceinline__ float oneplus_(float x) {
    return 1.f + fmaxf(x, 0.f) + log1pf(expf(-fabsf(x)));
}
__device__ __forceinline__ float wsum(float v) {
#pragma unroll
    for (int o = 32; o; o >>= 1) v += __shfl_xor(v, o, 64);
    return v;
}
__device__ __forceinline__ float wmaxr(float v) {
#pragma unroll
    for (int o = 32; o; o >>= 1) v = fmaxf(v, __shfl_xor(v, o, 64));
    return v;
}

// shared GEMV-partial body: contiguous half2 weight run (dwordx4 loads) dot
// half2 vector in LDS (b128 broadcasts) via v_dot2_f32_f16.
__device__ __attribute__((noinline)) float gemv_part(
    const __half2* __restrict__ wP, int iters,
    const __half2* __restrict__ vin)
{
    float a[8] = {0.f,0.f,0.f,0.f,0.f,0.f,0.f,0.f};
#pragma unroll 1
    for (int j0 = 0; j0 < iters; j0 += 8) {
        __half2 hh[8], vv[8];
        *(float4*)&hh[0] = *(const float4*)(wP + j0);
        *(float4*)&hh[4] = *(const float4*)(wP + j0 + 4);
        *(float4*)&vv[0] = *(const float4*)(vin + j0);
        *(float4*)&vv[4] = *(const float4*)(vin + j0 + 4);
#pragma unroll
        for (int u = 0; u < 8; ++u) a[u] = fdot2(hh[u], vv[u], a[u]);
    }
    return ((a[0]+a[1])+(a[2]+a[3])) + ((a[4]+a[5])+(a[6]+a[7]));
}

// ---- converter: fp32 weights -> packed half2, output-major ----
__global__ void convert_weights(const float* __restrict__ W1, const float* __restrict__ W2,
                                const float* __restrict__ Wif, const float* __restrict__ Wout,
                                const float* __restrict__ Wmem, __half2* __restrict__ wp) {
    int i = blockIdx.x * blockDim.x + threadIdx.x;
    if (i >= WTOT) return;
    float a, b;
    if (i < W2OFF)        { int n = i / 160, k2 = i - n * 160;            a = W1[(2*k2)*256+n];  b = W1[(2*k2+1)*256+n]; }
    else if (i < WIFOFF)  { int t = i - W2OFF;   int n = t >> 7, k2 = t & 127; a = W2[(2*k2)*256+n];  b = W2[(2*k2+1)*256+n]; }
    else if (i < WOUTOFF) { int t = i - WIFOFF;  int o = t >> 7, k2 = t & 127; a = Wif[(2*k2)*IFS+o]; b = Wif[(2*k2+1)*IFS+o]; }
    else if (i < WMEMOFF) { int t = i - WOUTOFF; int n = t >> 7, k2 = t & 127; a = Wout[(2*k2)*64+n]; b = Wout[(2*k2+1)*64+n]; }
    else                  { int t = i - WMEMOFF; int n = t >> 7, k2 = t & 127; a = Wmem[(2*k2)*64+n]; b = Wmem[(2*k2+1)*64+n]; }
    wp[i] = __floats2half2_rn(a, b);
}

template <bool LLINK>
__global__ __launch_bounds__(1024) void dnc_kernel(
    const float* __restrict__ x, const float* __restrict__ b1,
    const float* __restrict__ b2, const float* __restrict__ bif,
    const __half2* __restrict__ wp,
    __half* __restrict__ memg,      // per batch 64*256 halves, [w][n]
    __half* __restrict__ memTg,     // per batch 256*64 halves, [n][w] (transposed copy)
    __half2* __restrict__ linkg,    // fallback link
    float* __restrict__ out)
{
    extern __shared__ __align__(16) char smem[];
    const int b = blockIdx.x;
    const int tid = threadIdx.x;
    const int lane = tid & 63;
    const int wv = tid >> 6;

    __half2* l2p = (__half2*)smem;
    __half2* gl2 = linkg + (size_t)b * (256 * LROW);
    float* scr   = (float*)(smem + (LLINK ? LINKB : 0));
    __half* scrh = (__half*)scr;
    float* fx    = (float*)((char*)scr + SCRB);

    __half2* s_ctrlh = (__half2*)(fx + 0);        // 160: [0,32) x pairs, [32,160) rvec pairs
    __half2* s_hh    = (__half2*)(fx + 160);      // 128
    __half2* s_nnh   = (__half2*)(fx + 288);      // 128
    __half2* s_rwh   = (__half2*)(fx + 416);      // 512 [r][128 n-pairs]
    float* s_z     = fx + 928;    // 472
    float* s_usage = fx + 1400;   // 256
    float* s_ww    = fx + 1656;   // 256
    float* s_prec  = fx + 1912;   // 256
    float* s_wcdot = fx + 2168;   // 256
    float* s_wcss  = fx + 2424;   // 256
    float* s_knorm = fx + 2680;   // 4
    float* s_rstr  = fx + 2684;   // 4
    float* s_rmode = fx + 2688;   // 12
    float* s_sc    = fx + 2700;   // 4
    float* s_red   = fx + 2704;   // 32
    __half2* s_keyh = (__half2*)(fx + 2736);      // 128 half2 (=128 floats) [r][32 w-pairs]
    __half2* s_keyw = (__half2*)(fx + 2864);      // 32 half2 (write key pairs)
    float* s_er    = fx + 2896;   // 64 (erase gates, precomputed)  -> ends at 2960 = FIXF
    float* s_srt   = scr + 1024;  // 256 (mega only, B8..B9)
    float* s_cp    = scr + 1280;  // 256 (mega only, B8..B9)
    float* s_rwf   = scr + 1024;  // 1024 fp32 rw[n][r]; written P9b (B12..B13),
                                  // read P4 retention (B6..B7 next iter).
                                  // srt/cp (B8..B9) and P7 bwd (B9..B10) overwrite it
                                  // only AFTER P4 consumed it; P9b rewrites before next P4.

    __half*  memh  = memg + (size_t)b * (Ww * Nn);
    __half2* memh2 = (__half2*)memh;
    __half*  memT  = memTg + (size_t)b * (Nn * Ww);
    __half2* memT2 = (__half2*)memT;

    auto lread = [&](int idx) -> __half2 {
        if constexpr (LLINK) return l2p[idx]; else return gl2[idx];
    };
    auto lwrite = [&](int idx, __half2 v) {
        if constexpr (LLINK) l2p[idx] = v; else gl2[idx] = v;
    };

    // ---- init (ws/LDS poisoned before every launch) ----
    {
        __half2 z2 = pkh(0.f, 0.f);
#pragma unroll 1
        for (int i = tid; i < 256 * LROW; i += 1024) lwrite(i, z2);
        __half2 e2 = __floats2half2_rn(EPSf, EPSf);
#pragma unroll 1
        for (int j = 0; j < 8; ++j) { memh2[tid + j * 1024] = e2; memT2[tid + j * 1024] = e2; }
        if (tid < 512) s_rwh[tid] = z2;
        if (tid < 32) {
            float2 xv = *(const float2*)&x[b * INd + 2 * tid];
            s_ctrlh[tid] = pkh(xv.x, xv.y);
        } else if (tid < 160) s_ctrlh[tid] = z2;
        s_rwf[tid] = 0.f;
    }
    if (tid < 256) {
        s_usage[tid] = 0.f; s_ww[tid] = 0.f; s_prec[tid] = 0.f;
    }

#pragma unroll 1
    for (int t = 0; t < Tt; ++t) {
        __syncthreads();  // B0

        // ---- P1: GEMV1 partials ----
        {
            int kc = wv >> 2, o = (wv & 3) * 64 + lane;
            scr[kc * 256 + o] = gemv_part(wp + W1OFF + o * 160 + kc * 40, 40,
                                          s_ctrlh + kc * 40);
        }
        __syncthreads();  // B1
        if (tid < 256) {
            float v = tanhf(b1[tid] + ((scr[tid] + scr[256+tid]) + (scr[512+tid] + scr[768+tid])));
            float pv = __shfl_xor(v, 1, 64);
            if ((tid & 1) == 0) s_hh[tid >> 1] = pkh(v, pv);
        }
        __syncthreads();  // B2

        // ---- P2: GEMV2 partials ----
        {
            int kc = wv >> 2, o = (wv & 3) * 64 + lane;
            scr[kc * 256 + o] = gemv_part(wp + W2OFF + o * 128 + kc * 32, 32,
                                          s_hh + kc * 32);
        }
        __syncthreads();  // B3
        if (tid < 256) {
            float v = tanhf(b2[tid] + ((scr[tid] + scr[256+tid]) + (scr[512+tid] + scr[768+tid])));
            float pv = __shfl_xor(v, 1, 64);
            if ((tid & 1) == 0) s_nnh[tid >> 1] = pkh(v, pv);
        }
        __syncthreads();  // B4

        // ---- P3: GEMV3 partials ----
        {
            int kc = wv >> 3, o = (wv & 7) * 64 + lane;
            if (o < IFS)
                scr[kc * 512 + o] = gemv_part(wp + WIFOFF + o * 128 + kc * 64, 64,
                                              s_nnh + kc * 64);
        }
        __syncthreads();  // B5
        // s_z + packed key copies (read keys along w per r; write key pairs)
        if (tid < IFS) {
            float v = bif[tid] + scr[tid] + scr[512 + tid];
            s_z[tid] = v;
            float pv1 = __shfl_xor(v, 1, 64);
            float pv4 = __shfl_xor(v, 4, 64);
            if (tid < 256) {
                int r = tid & 3, w = tid >> 2;
                if ((w & 1) == 0) s_keyh[r * 32 + (w >> 1)] = pkh(v, pv4);
            } else if (tid >= 260 && tid < 324) {
                if ((tid & 1) == 0) s_keyw[(tid - 260) >> 1] = pkh(v, pv1);
            }
        }
        __syncthreads();  // B6

        // ---- P4: scalars + usage + wc dot/ss (merged wave roles) ----
        if (wv < 4) {
            float vz = s_z[lane * 4 + wv];
            float s = wsum(vz * vz);
            if (lane == 0) s_knorm[wv] = sqrtf(s) + EPSf;
        } else if (wv == 4) {
            float vz = s_z[260 + lane];
            float s = wsum(vz * vz);
            if (lane == 0) s_sc[3] = sqrtf(s) + EPSf;
        } else if (wv == 5) {
            if (lane < 4) s_rstr[lane] = oneplus_(s_z[256 + lane]);
            else if (lane >= 8 && lane < 12) {
                int r = lane - 8;
                float a = s_z[459+r], bm = s_z[463+r], c = s_z[467+r];
                float mx = fmaxf(a, fmaxf(bm, c));
                float ea = expf(a-mx), eb = expf(bm-mx), ec = expf(c-mx);
                float inv = 1.f / ((ea+eb)+ec);
                s_rmode[0*4+r] = ea*inv; s_rmode[1*4+r] = eb*inv; s_rmode[2*4+r] = ec*inv;
            } else if (lane == 16) s_sc[0] = oneplus_(s_z[324]);
            else if (lane == 17) s_sc[1] = sigm(s_z[457]);
            else if (lane == 18) s_sc[2] = sigm(s_z[458]);
        } else if (wv == 6) {
            s_er[lane] = sigm(s_z[325 + lane]);   // erase gates, once
        } else if (wv >= 8 && wv < 12) {
            int n = tid - 512;
            float ret = 1.f;
#pragma unroll
            for (int r = 0; r < 4; ++r) {
                float fg = sigm(s_z[453 + r]);
                ret *= 1.f - fg * s_rwf[n*4 + r];
            }
            float u = s_usage[n], wwo = s_ww[n];
            s_usage[n] = (u + wwo - u * wwo) * ret;
        } else if (wv >= 12) {
            int n = tid - 768;
            const __half2* mT2r = (const __half2*)(memT + n * 64);
            float dot = 0.f, ssv = 0.f;
#pragma unroll
            for (int c = 0; c < 8; ++c) {
                __half2 mv[4], kv[4];
                *(float4*)mv = *(const float4*)(mT2r + c * 4);
                *(float4*)kv = *(const float4*)(s_keyw + c * 4);
#pragma unroll
                for (int u = 0; u < 4; ++u) {
                    ssv = fdot2(mv[u], mv[u], ssv);
                    dot = fdot2(mv[u], kv[u], dot);
                }
            }
            s_wcdot[n] = dot; s_wcss[n] = ssv;
        }
        __syncthreads();  // B7

        // ---- P5: rank partials (float4 broadcast reads of usage) ----
        {
            int q = tid >> 8, n = tid & 255;
            float un = s_usage[n];
            float cnt = 0.f;
            int j0 = q * 64;
#pragma unroll 1
            for (int j = j0; j < j0 + 64; j += 4) {
                float4 uv = *(const float4*)&s_usage[j];
                cnt += (uv.x < un || (uv.x == un && j     < n)) ? 1.f : 0.f;
                cnt += (uv.y < un || (uv.y == un && j + 1 < n)) ? 1.f : 0.f;
                cnt += (uv.z < un || (uv.z == un && j + 2 < n)) ? 1.f : 0.f;
                cnt += (uv.w < un || (uv.w == un && j + 3 < n)) ? 1.f : 0.f;
            }
            scr[q * 256 + n] = cnt;
        }
        __syncthreads();  // B8

        // ---- P6: mega (wave 0) ----
        if (wv == 0) {
            int rk[4]; float uu[4];
#pragma unroll
            for (int i = 0; i < 4; ++i) {
                int n = lane * 4 + i;
                float c = scr[n] + scr[256+n] + scr[512+n] + scr[768+n];
                rk[i] = (int)(c + 0.5f);
                uu[i] = s_usage[n];
                s_srt[rk[i]] = uu[i];
            }
            float4 vs = ((const float4*)s_srt)[lane];
            float p1 = vs.x * vs.y, p2 = p1 * vs.z, tot = p2 * vs.w;
            float incl = tot;
#pragma unroll
            for (int off = 1; off < 64; off <<= 1) {
                float tv = __shfl_up(incl, off, 64);
                if (lane >= off) incl *= tv;
            }
            float excl = __shfl_up(incl, 1, 64);
            if (lane == 0) excl = 1.f;
            float4 o4v; o4v.x = excl; o4v.y = excl*vs.x; o4v.z = excl*p1; o4v.w = excl*p2;
            ((float4*)s_cp)[lane] = o4v;

            float sims[4], mx = -1e30f;
#pragma unroll
            for (int i = 0; i < 4; ++i) {
                int n = lane * 4 + i;
                sims[i] = s_wcdot[n] / ((sqrtf(s_wcss[n]) + EPSf) * s_sc[3]) * s_sc[0];
                mx = fmaxf(mx, sims[i]);
            }
            mx = wmaxr(mx);
            float es[4], ls = 0.f;
#pragma unroll
            for (int i = 0; i < 4; ++i) { es[i] = expf(sims[i] - mx); ls += es[i]; }
            ls = wsum(ls);
            float ag = s_sc[1], wg = s_sc[2], inv = 1.f / ls, lw = 0.f;
#pragma unroll
            for (int i = 0; i < 4; ++i) {
                int n = lane * 4 + i;
                float alloc = (1.f - uu[i]) * s_cp[rk[i]];
                float wwn = wg * (ag * alloc + (1.f - ag) * es[i] * inv);
                s_ww[n] = wwn; lw += wwn;
            }
            lw = wsum(lw);
            if (lane == 0) s_red[0] = lw;
        }
        __syncthreads();  // B9

        // ---- P7: link col pass (8 waves; bwd via fdot2) || mem RMW (8 waves) ----
        if (tid < 512) {
            int kc = tid >> 7, p = tid & 127;
            int c0 = 2 * p, c1 = c0 + 1;
            float wwc0 = s_ww[c0], wwc1 = s_ww[c1];
            float pt0 = s_prec[c0], pt1 = s_prec[c1];
            float acc[8] = {0,0,0,0,0,0,0,0};
            int kbase = kc * 64;
#pragma unroll 1
            for (int k0 = kbase; k0 < kbase + 64; k0 += 8) {
                __half2 lv[8];
#pragma unroll
                for (int u = 0; u < 8; ++u) lv[u] = lread((k0 + u) * LROW + p);
                float wk8[8];
                *(float4*)&wk8[0] = *(const float4*)&s_ww[k0];
                *(float4*)&wk8[4] = *(const float4*)&s_ww[k0 + 4];
                float l0v[8], l1v[8];
#pragma unroll
                for (int u = 0; u < 8; ++u) {
                    int k = k0 + u;
                    float wk = wk8[u];
                    float2 lf = __half22float2(lv[u]);
                    float l0 = (1.f - wk - wwc0) * lf.x + wk * pt0;
                    float l1 = (1.f - wk - wwc1) * lf.y + wk * pt1;
                    if (k == c0) l0 = 0.f;
                    if (k == c1) l1 = 0.f;
                    l0v[u] = l0; l1v[u] = l1;
                }
#pragma unroll
                for (int u = 0; u < 8; ++u)
                    lwrite((k0 + u) * LROW + p, pkh(l0v[u], l1v[u]));
                __half2 l0p[4], l1p[4];
#pragma unroll
                for (int i = 0; i < 4; ++i) {
                    l0p[i] = pkh(l0v[2*i], l0v[2*i+1]);
                    l1p[i] = pkh(l1v[2*i], l1v[2*i+1]);
                }
                int kp0 = k0 >> 1;
#pragma unroll
                for (int r = 0; r < 4; ++r) {
                    __half2 rp[4];
                    *(float4*)rp = *(const float4*)(s_rwh + r * 128 + kp0);
#pragma unroll
                    for (int i = 0; i < 4; ++i) {
                        acc[r]     = fdot2(l0p[i], rp[i], acc[r]);
                        acc[4 + r] = fdot2(l1p[i], rp[i], acc[4 + r]);
                    }
                }
            }
            __half2* bp = (__half2*)scrh + (kc * 128 + p) * 4;
            bp[0] = pkh(acc[0], acc[1]);
            bp[1] = pkh(acc[2], acc[3]);
            bp[2] = pkh(acc[4], acc[5]);
            bp[3] = pkh(acc[6], acc[7]);
        } else {
            int t0 = tid - 512;
#pragma unroll 1
            for (int jb = 0; jb < 2; ++jb) {
                __half2 mv[8];
#pragma unroll
                for (int j = 0; j < 8; ++j) mv[j] = memh2[t0 + (jb * 8 + j) * 512];
#pragma unroll
                for (int j = 0; j < 8; ++j) {
                    int i2 = t0 + (jb * 8 + j) * 512;
                    int w = i2 >> 7, n2 = i2 & 127;
                    float er = s_er[w];
                    float wvv = s_z[389 + w];
                    float2 mf = __half22float2(mv[j]);
                    float wa = s_ww[2*n2], wb = s_ww[2*n2 + 1];
                    mf.x = mf.x * (1.f - wa * er) + wa * wvv;
                    mf.y = mf.y * (1.f - wb * er) + wb * wvv;
                    __half2 hv = __floats2half2_rn(mf.x, mf.y);
                    memh2[i2] = hv;
                    memT[(2*n2)     * 64 + w] = __low2half(hv);   // keep transpose in sync
                    memT[(2*n2 + 1) * 64 + w] = __high2half(hv);
                }
            }
        }
        __syncthreads();  // B10

        // ---- P8: fwd row pass (fdot2, b128 rp broadcasts) + prec update ----
        {
            int q = tid >> 8, n8 = tid & 255;
            float f[4] = {0.f, 0.f, 0.f, 0.f};
            int base = n8 * LROW + q * 32;
#pragma unroll 1
            for (int j0 = 0; j0 < 32; j0 += 8) {
                __half2 lv[8];
#pragma unroll
                for (int u = 0; u < 8; ++u) lv[u] = lread(base + j0 + u);
#pragma unroll
                for (int r = 0; r < 4; ++r) {
                    __half2 rp[8];
                    *(float4*)&rp[0] = *(const float4*)(s_rwh + r * 128 + q * 32 + j0);
                    *(float4*)&rp[4] = *(const float4*)(s_rwh + r * 128 + q * 32 + j0 + 4);
#pragma unroll
                    for (int u = 0; u < 8; ++u) f[r] = fdot2(lv[u], rp[u], f[r]);
                }
            }
            __half2* fp2 = (__half2*)(scrh + 4096) + (q * 256 + n8) * 2;
            fp2[0] = pkh(f[0], f[1]);
            fp2[1] = pkh(f[2], f[3]);
            if (q == 0) s_prec[n8] = (1.f - s_red[0]) * s_prec[n8] + s_ww[n8];
        }
        __syncthreads();  // B11

        // ---- P9: rc sim via memT rows + bwd/fwd reduce ----
        int rr = tid >> 8, n8c = tid & 255;
        float bwv = 0.f, fwv = 0.f, e_rc = 0.f;
        {
#pragma unroll
            for (int kc = 0; kc < 4; ++kc)
                bwv += __half2float(scrh[(kc * 128 + (n8c >> 1)) * 8 + (n8c & 1) * 4 + rr]);
#pragma unroll
            for (int qq = 0; qq < 4; ++qq)
                fwv += __half2float(scrh[4096 + (qq * 256 + n8c) * 4 + rr]);
            const __half2* mT2r = (const __half2*)(memT + n8c * 64);
            const __half2* kh = s_keyh + rr * 32;
            float ssv = 0.f, dv = 0.f;
#pragma unroll
            for (int c = 0; c < 8; ++c) {
                __half2 mv[4], kv[4];
                *(float4*)mv = *(const float4*)(mT2r + c * 4);
                *(float4*)kv = *(const float4*)(kh + c * 4);
#pragma unroll
                for (int u = 0; u < 4; ++u) {
                    ssv = fdot2(mv[u], mv[u], ssv);
                    dv  = fdot2(mv[u], kv[u], dv);
                }
            }
            float sim = dv / ((sqrtf(ssv) + EPSf) * s_knorm[rr]) * s_rstr[rr];
            e_rc = expf(sim);        // |sim| small (strength-scaled cosine); R11/R13-verified
            float s = wsum(e_rc);
            if (lane == 0) s_red[16 + wv] = s;
        }
        __syncthreads();  // B12
        {
            float sm = (s_red[16+rr*4+0] + s_red[16+rr*4+1]) + (s_red[16+rr*4+2] + s_red[16+rr*4+3]);
            float rc = e_rc / sm;
            float v = bwv * s_rmode[0*4+rr] + rc * s_rmode[1*4+rr] + fwv * s_rmode[2*4+rr];
            s_rwf[n8c*4 + rr] = v;                    // fp32 copy for retention
            float pv = __shfl_xor(v, 1, 64);
            if ((n8c & 1) == 0) s_rwh[rr * 128 + (n8c >> 1)] = pkh(v, pv);
        }
        __syncthreads();  // B13

        // ---- P12: rvec partials (pure fdot2: memh rows x s_rwh pairs) ----
        {
            int kc = tid >> 8, o = tid & 255, w = o >> 2, r = o & 3;
            const __half2* mw2 = (const __half2*)(memh + w * 256 + kc * 64);
            const __half2* rw2 = s_rwh + r * 128 + kc * 32;
            float a = 0.f;
#pragma unroll
            for (int c = 0; c < 8; ++c) {
                __half2 mv[4], rv[4];
                *(float4*)mv = *(const float4*)(mw2 + c * 4);
                *(float4*)rv = *(const float4*)(rw2 + c * 4);
#pragma unroll
                for (int u = 0; u < 4; ++u) a = fdot2(mv[u], rv[u], a);
            }
            scr[kc * 256 + o] = a;
        }
        __syncthreads();  // B14

        // ---- P13: rvec reduce -> ctrl pairs + next-x staging ----
        if (tid < 256) {
            float v = (scr[tid] + scr[256+tid]) + (scr[512+tid] + scr[768+tid]);
            float pv = __shfl_xor(v, 1, 64);
            if ((tid & 1) == 0) s_ctrlh[32 + (tid >> 1)] = pkh(v, pv);
        } else if (tid >= 512 && tid < 544) {
            if (t + 1 < Tt) {
                int i = tid - 512;
                float2 xv = *(const float2*)&x[((t + 1) * Bb + b) * INd + 2 * i];
                s_ctrlh[i] = pkh(xv.x, xv.y);
            }
        }
        __syncthreads();  // B15

        // ---- P14: out GEMV partials ----
        {
            int c4 = wv, o4 = lane;
            const __half2* wsrc = (c4 < 8) ? (wp + WOUTOFF + o4 * 128 + c4 * 16)
                                           : (wp + WMEMOFF + o4 * 128 + (c4 - 8) * 16);
            const __half2* vsrc = (c4 < 8) ? (s_nnh + c4 * 16)
                                           : (s_ctrlh + 32 + (c4 - 8) * 16);
            scr[c4 * 64 + o4] = gemv_part(wsrc, 16, vsrc);
        }
        __syncthreads();  // B16
        if (tid < 64) {
            float s = 0.f;
#pragma unroll
            for (int g = 0; g < 16; ++g) s += scr[g * 64 + tid];
            out[(t * Bb + b) * OUTd + tid] = s;
        }
        // loop-top barrier covers remaining hazards
    }
}

extern "C" void kernel_launch(void* const* d_in, const int* in_sizes, int n_in,
                              void* d_out, int out_size, void* d_ws, size_t ws_size,
                              hipStream_t stream) {
    const float* x    = (const float*)d_in[0];
    const float* W1   = (const float*)d_in[1];
    const float* b1   = (const float*)d_in[2];
    const float* W2   = (const float*)d_in[3];
    const float* b2   = (const float*)d_in[4];
    const float* Wif  = (const float*)d_in[5];
    const float* bif  = (const float*)d_in[6];
    const float* Wout = (const float*)d_in[7];
    const float* Wmem = (const float*)d_in[8];
    float* out = (float*)d_out;

    // ws: [0, 601600) packed half2 weights; then mem fp16 (512KB); then memT (512KB);
    // then fallback link.
    char* ws = (char*)d_ws;
    __half2* wp    = (__half2*)ws;
    __half*  memg  = (__half*)(ws + 601600);
    __half*  memTg = (__half*)(ws + 601600 + 524288);
    __half2* linkg = (__half2*)(ws + 601600 + 524288 + 524288);

    convert_weights<<<dim3((WTOT + 255) / 256), dim3(256), 0, stream>>>(W1, W2, Wif, Wout, Wmem, wp);

    hipError_t rc = hipFuncSetAttribute(
        reinterpret_cast<const void*>(&dnc_kernel<true>),
        hipFuncAttributeMaxDynamicSharedMemorySize, SMEM_MAIN);
    if (rc == hipSuccess) {
        dnc_kernel<true><<<dim3(Bb), dim3(1024), SMEM_MAIN, stream>>>(
            x, b1, b2, bif, wp, memg, memTg, linkg, out);
    } else {
        dnc_kernel<false><<<dim3(Bb), dim3(1024), SMEM_FB, stream>>>(
            x, b1, b2, bif, wp, memg, memTg, linkg, out);
    }
}

// Round 4
// 1998.582 us; speedup vs baseline: 1.4950x; 1.4950x over previous
//
#include <hip/hip_runtime.h>
#include <hip/hip_fp16.h>
#include <math.h>

#define Tt 64
#define Bb 16
#define Nn 256
#define Ww 64
#define Rr 4
#define INd 64
#define OUTd 64
#define IFS 471
#define EPSf 1e-6f

// packed half2 weight layout: quad-of-k2 per column, wave-coalesced.
// index = OFF + ((k2>>2)*Ncol + n)*4 + (k2&3); lane n loads dwordx4 (4 k2-pairs),
// consecutive lanes 16B apart -> 1KiB per wave per load instruction.
#define W1OFF   0        // K2=160, Ncol=256 -> 40960
#define W2OFF   40960    // K2=128, Ncol=256 -> 32768
#define WIFOFF  73728    // K2=128, Ncol=471 -> 60288
#define WOUTOFF 134016   // K2=128, Ncol=64  -> 8192
#define WMEMOFF 142208   // K2=128, Ncol=64  -> 8192
#define WTOT    150400

// link: 256 rows x 129 dwords (258 halfs; 256 used + 2 pad)
#define LROW    129
#define LINKB   (256 * LROW * 4)     // 132096 B
#define SCRB    16384                // 4096 floats / 8192 halfs
#define FIXF    3824
#define SMEM_MAIN (LINKB + SCRB + FIXF * 4)   // 163776 <= 163840
#define SMEM_FB   (SCRB + FIXF * 4)

typedef _Float16 h2v __attribute__((ext_vector_type(2)));
__device__ __forceinline__ float fdot2(__half2 a, __half2 b, float c) {
    return __builtin_amdgcn_fdot2(*(h2v*)&a, *(h2v*)&b, c, false);
}
__device__ __forceinline__ __half2 pkh(float a, float b) {
    auto r = __builtin_amdgcn_cvt_pkrtz(a, b);   // __fp16 ext_vector(2)
    return *(__half2*)&r;
}

__device__ __forceinline__ float sigm(float x) { return 1.f / (1.f + expf(-x)); }
__device__ __forceinline__ float oneplus_(float x) {
    return 1.f + fmaxf(x, 0.f) + log1pf(expf(-fabsf(x)));
}
__device__ __forceinline__ float wsum(float v) {
#pragma unroll
    for (int o = 32; o; o >>= 1) v += __shfl_xor(v, o, 64);
    return v;
}
__device__ __forceinline__ float wmaxr(float v) {
#pragma unroll
    for (int o = 32; o; o >>= 1) v = fmaxf(v, __shfl_xor(v, o, 64));
    return v;
}

// shared GEMV-partial body. wP = column base (wp + OFF + n*4), str = Ncol*4
// (half2 units per k8 block), iters in k2 units (multiple of 8).
// Weight loads: dwordx4 per lane, wave-coalesced (lanes 16B apart).
// Vector operand: wave-uniform b128 LDS broadcasts.
__device__ __attribute__((noinline)) float gemv_part(
    const __half2* __restrict__ wP, int str, int iters,
    const __half2* __restrict__ vin)
{
    float a[8] = {0.f,0.f,0.f,0.f,0.f,0.f,0.f,0.f};
#pragma unroll 1
    for (int j0 = 0; j0 < iters; j0 += 8) {
        __half2 hh[8], vv[8];
        int k8 = j0 >> 2;
        *(float4*)&hh[0] = *(const float4*)(wP + (size_t)k8 * str);
        *(float4*)&hh[4] = *(const float4*)(wP + (size_t)(k8 + 1) * str);
        *(float4*)&vv[0] = *(const float4*)(vin + j0);
        *(float4*)&vv[4] = *(const float4*)(vin + j0 + 4);
#pragma unroll
        for (int u = 0; u < 8; ++u) a[u] = fdot2(hh[u], vv[u], a[u]);
    }
    return ((a[0]+a[1])+(a[2]+a[3])) + ((a[4]+a[5])+(a[6]+a[7]));
}

// ---- converter: fp32 weights -> packed half2 quad layout ----
__global__ void convert_weights(const float* __restrict__ W1, const float* __restrict__ W2,
                                const float* __restrict__ Wif, const float* __restrict__ Wout,
                                const float* __restrict__ Wmem, __half2* __restrict__ wp) {
    int i = blockIdx.x * blockDim.x + threadIdx.x;
    if (i >= WTOT) return;
    float a, b;
    if (i < W2OFF) {
        int q = i & 3, s = i >> 2, n = s & 255, k2 = (s >> 8) * 4 + q;
        a = W1[(2*k2)*256+n];  b = W1[(2*k2+1)*256+n];
    } else if (i < WIFOFF) {
        int t = i - W2OFF;
        int q = t & 3, s = t >> 2, n = s & 255, k2 = (s >> 8) * 4 + q;
        a = W2[(2*k2)*256+n];  b = W2[(2*k2+1)*256+n];
    } else if (i < WOUTOFF) {
        int t = i - WIFOFF;
        int q = t & 3, s = t >> 2, o = s % IFS, k2 = (s / IFS) * 4 + q;
        a = Wif[(2*k2)*IFS+o]; b = Wif[(2*k2+1)*IFS+o];
    } else if (i < WMEMOFF) {
        int t = i - WOUTOFF;
        int q = t & 3, s = t >> 2, n = s & 63, k2 = (s >> 6) * 4 + q;
        a = Wout[(2*k2)*64+n]; b = Wout[(2*k2+1)*64+n];
    } else {
        int t = i - WMEMOFF;
        int q = t & 3, s = t >> 2, n = s & 63, k2 = (s >> 6) * 4 + q;
        a = Wmem[(2*k2)*64+n]; b = Wmem[(2*k2+1)*64+n];
    }
    wp[i] = __floats2half2_rn(a, b);
}

template <bool LLINK>
__global__ __launch_bounds__(1024) void dnc_kernel(
    const float* __restrict__ x, const float* __restrict__ b1,
    const float* __restrict__ b2, const float* __restrict__ bif,
    const __half2* __restrict__ wp,
    __half* __restrict__ memg,      // per batch 64*256 halves, [w][n]
    __half2* __restrict__ linkg,    // fallback link
    float* __restrict__ out)
{
    extern __shared__ __align__(16) char smem[];
    const int b = blockIdx.x;
    const int tid = threadIdx.x;
    const int lane = tid & 63;
    const int wv = tid >> 6;

    __half2* l2p = (__half2*)smem;
    __half2* gl2 = linkg + (size_t)b * (256 * LROW);
    float* scr   = (float*)(smem + (LLINK ? LINKB : 0));
    __half* scrh = (__half*)scr;
    float* fx    = (float*)((char*)scr + SCRB);

    float*   s_rw    = fx + 0;                    // 1024 [n][r] fp32
    __half2* s_ctrlh = (__half2*)(fx + 1024);     // 160: [0,32) x pairs, [32,160) rvec pairs
    __half2* s_hh    = (__half2*)(fx + 1184);     // 128
    __half2* s_nnh   = (__half2*)(fx + 1312);     // 128
    __half2* s_rwh   = (__half2*)(fx + 1440);     // 512 [r][128 n-pairs]
    float* s_z     = fx + 1952;   // 472
    float* s_usage = fx + 2424;   // 256
    float* s_ww    = fx + 2680;   // 256
    float* s_prec  = fx + 2936;   // 256
    float* s_wcdot = fx + 3192;   // 256
    float* s_wcss  = fx + 3448;   // 256
    float* s_knorm = fx + 3704;   // 4
    float* s_rstr  = fx + 3708;   // 4
    float* s_rmode = fx + 3712;   // 12
    float* s_sc    = fx + 3724;   // 4
    float* s_red   = fx + 3728;   // 32
    float* s_er    = fx + 3760;   // 64 (erase gates, precomputed) -> 3824 = FIXF
    float* s_srt   = scr + 1024;  // 256 (mega only)
    float* s_cp    = scr + 1280;  // 256 (mega only)

    __half*  memh  = memg + (size_t)b * (Ww * Nn);
    __half2* memh2 = (__half2*)memh;

    auto lread = [&](int idx) -> __half2 {
        if constexpr (LLINK) return l2p[idx]; else return gl2[idx];
    };
    auto lwrite = [&](int idx, __half2 v) {
        if constexpr (LLINK) l2p[idx] = v; else gl2[idx] = v;
    };

    // ---- init (ws/LDS poisoned before every launch) ----
    {
        __half2 z2 = pkh(0.f, 0.f);
#pragma unroll 1
        for (int i = tid; i < 256 * LROW; i += 1024) lwrite(i, z2);
        __half2 e2 = __floats2half2_rn(EPSf, EPSf);
#pragma unroll 1
        for (int j = 0; j < 8; ++j) memh2[tid + j * 1024] = e2;
        if (tid < 512) s_rwh[tid] = z2;
        if (tid < 32) {
            float2 xv = *(const float2*)&x[b * INd + 2 * tid];
            s_ctrlh[tid] = pkh(xv.x, xv.y);
        } else if (tid < 160) s_ctrlh[tid] = z2;
    }
    if (tid < 256) {
        s_usage[tid] = 0.f; s_ww[tid] = 0.f; s_prec[tid] = 0.f;
        s_rw[tid*4+0] = 0.f; s_rw[tid*4+1] = 0.f; s_rw[tid*4+2] = 0.f; s_rw[tid*4+3] = 0.f;
    }

#pragma unroll 1
    for (int t = 0; t < Tt; ++t) {
        __syncthreads();  // B0

        // ---- P1: GEMV1 partials ----
        {
            int kc = wv >> 2, o = (wv & 3) * 64 + lane;
            scr[kc * 256 + o] = gemv_part(wp + W1OFF + o * 4 + kc * 10240, 1024, 40,
                                          s_ctrlh + kc * 40);
        }
        __syncthreads();  // B1
        if (tid < 256) {
            float v = tanhf(b1[tid] + ((scr[tid] + scr[256+tid]) + (scr[512+tid] + scr[768+tid])));
            float pv = __shfl_xor(v, 1, 64);
            if ((tid & 1) == 0) s_hh[tid >> 1] = pkh(v, pv);
        }
        __syncthreads();  // B2

        // ---- P2: GEMV2 partials ----
        {
            int kc = wv >> 2, o = (wv & 3) * 64 + lane;
            scr[kc * 256 + o] = gemv_part(wp + W2OFF + o * 4 + kc * 8192, 1024, 32,
                                          s_hh + kc * 32);
        }
        __syncthreads();  // B3
        if (tid < 256) {
            float v = tanhf(b2[tid] + ((scr[tid] + scr[256+tid]) + (scr[512+tid] + scr[768+tid])));
            float pv = __shfl_xor(v, 1, 64);
            if ((tid & 1) == 0) s_nnh[tid >> 1] = pkh(v, pv);
        }
        __syncthreads();  // B4

        // ---- P3: GEMV3 partials ----
        {
            int kc = wv >> 3, o = (wv & 7) * 64 + lane;
            if (o < IFS)
                scr[kc * 512 + o] = gemv_part(wp + WIFOFF + o * 4 + kc * 30144, 1884, 64,
                                              s_nnh + kc * 64);
        }
        __syncthreads();  // B5
        if (tid < IFS) s_z[tid] = bif[tid] + scr[tid] + scr[512 + tid];
        __syncthreads();  // B6

        // ---- P4: scalars + usage + wc dot/ss (merged wave roles) ----
        if (wv < 4) {
            float vz = s_z[lane * 4 + wv];
            float s = wsum(vz * vz);
            if (lane == 0) s_knorm[wv] = sqrtf(s) + EPSf;
        } else if (wv == 4) {
            float vz = s_z[260 + lane];
            float s = wsum(vz * vz);
            if (lane == 0) s_sc[3] = sqrtf(s) + EPSf;
        } else if (wv == 5) {
            if (lane < 4) s_rstr[lane] = oneplus_(s_z[256 + lane]);
            else if (lane >= 8 && lane < 12) {
                int r = lane - 8;
                float a = s_z[459+r], bm = s_z[463+r], c = s_z[467+r];
                float mx = fmaxf(a, fmaxf(bm, c));
                float ea = expf(a-mx), eb = expf(bm-mx), ec = expf(c-mx);
                float inv = 1.f / ((ea+eb)+ec);
                s_rmode[0*4+r] = ea*inv; s_rmode[1*4+r] = eb*inv; s_rmode[2*4+r] = ec*inv;
            } else if (lane == 16) s_sc[0] = oneplus_(s_z[324]);
            else if (lane == 17) s_sc[1] = sigm(s_z[457]);
            else if (lane == 18) s_sc[2] = sigm(s_z[458]);
        } else if (wv == 6) {
            s_er[lane] = sigm(s_z[325 + lane]);   // erase gates, once per step
        } else if (wv >= 8 && wv < 12) {
            int n = tid - 512;
            float ret = 1.f;
#pragma unroll
            for (int r = 0; r < 4; ++r) {
                float fg = sigm(s_z[453 + r]);
                ret *= 1.f - fg * s_rw[n*4 + r];
            }
            float u = s_usage[n], wwo = s_ww[n];
            s_usage[n] = (u + wwo - u * wwo) * ret;
        } else if (wv >= 12) {
            int n = tid - 768;
            float dot = 0.f, ssv = 0.f;
#pragma unroll 1
            for (int w0 = 0; w0 < 64; w0 += 16) {
                __half hv[16];
#pragma unroll
                for (int u = 0; u < 16; ++u) hv[u] = memh[(w0 + u) * 256 + n];
#pragma unroll
                for (int u = 0; u < 16; ++u) {
                    float m = __half2float(hv[u]);
                    ssv = fmaf(m, m, ssv);
                    dot = fmaf(m, s_z[260 + w0 + u], dot);
                }
            }
            s_wcdot[n] = dot; s_wcss[n] = ssv;
        }
        __syncthreads();  // B7

        // ---- P5: rank partials (float4 broadcast reads of usage) ----
        {
            int q = tid >> 8, n = tid & 255;
            float un = s_usage[n];
            float cnt = 0.f;
            int j0 = q * 64;
#pragma unroll 1
            for (int j = j0; j < j0 + 64; j += 4) {
                float4 uv = *(const float4*)&s_usage[j];
                cnt += (uv.x < un || (uv.x == un && j     < n)) ? 1.f : 0.f;
                cnt += (uv.y < un || (uv.y == un && j + 1 < n)) ? 1.f : 0.f;
                cnt += (uv.z < un || (uv.z == un && j + 2 < n)) ? 1.f : 0.f;
                cnt += (uv.w < un || (uv.w == un && j + 3 < n)) ? 1.f : 0.f;
            }
            scr[q * 256 + n] = cnt;
        }
        __syncthreads();  // B8

        // ---- P6: mega (wave 0) ----
        if (wv == 0) {
            int rk[4]; float uu[4];
#pragma unroll
            for (int i = 0; i < 4; ++i) {
                int n = lane * 4 + i;
                float c = scr[n] + scr[256+n] + scr[512+n] + scr[768+n];
                rk[i] = (int)(c + 0.5f);
                uu[i] = s_usage[n];
                s_srt[rk[i]] = uu[i];
            }
            float4 vs = ((const float4*)s_srt)[lane];
            float p1 = vs.x * vs.y, p2 = p1 * vs.z, tot = p2 * vs.w;
            float incl = tot;
#pragma unroll
            for (int off = 1; off < 64; off <<= 1) {
                float tv = __shfl_up(incl, off, 64);
                if (lane >= off) incl *= tv;
            }
            float excl = __shfl_up(incl, 1, 64);
            if (lane == 0) excl = 1.f;
            float4 o4v; o4v.x = excl; o4v.y = excl*vs.x; o4v.z = excl*p1; o4v.w = excl*p2;
            ((float4*)s_cp)[lane] = o4v;

            float sims[4], mx = -1e30f;
#pragma unroll
            for (int i = 0; i < 4; ++i) {
                int n = lane * 4 + i;
                sims[i] = s_wcdot[n] / ((sqrtf(s_wcss[n]) + EPSf) * s_sc[3]) * s_sc[0];
                mx = fmaxf(mx, sims[i]);
            }
            mx = wmaxr(mx);
            float es[4], ls = 0.f;
#pragma unroll
            for (int i = 0; i < 4; ++i) { es[i] = expf(sims[i] - mx); ls += es[i]; }
            ls = wsum(ls);
            float ag = s_sc[1], wg = s_sc[2], inv = 1.f / ls, lw = 0.f;
#pragma unroll
            for (int i = 0; i < 4; ++i) {
                int n = lane * 4 + i;
                float alloc = (1.f - uu[i]) * s_cp[rk[i]];
                float wwn = wg * (ag * alloc + (1.f - ag) * es[i] * inv);
                s_ww[n] = wwn; lw += wwn;
            }
            lw = wsum(lw);
            if (lane == 0) s_red[0] = lw;
        }
        __syncthreads();  // B9

        // ---- P7: link col pass (8 waves; bwd via fdot2) || mem RMW (8 waves) ----
        if (tid < 512) {
            int kc = tid >> 7, p = tid & 127;
            int c0 = 2 * p, c1 = c0 + 1;
            float wwc0 = s_ww[c0], wwc1 = s_ww[c1];
            float pt0 = s_prec[c0], pt1 = s_prec[c1];
            float acc[8] = {0,0,0,0,0,0,0,0};
            int kbase = kc * 64;
#pragma unroll 1
            for (int k0 = kbase; k0 < kbase + 64; k0 += 8) {
                __half2 lv[8];
#pragma unroll
                for (int u = 0; u < 8; ++u) lv[u] = lread((k0 + u) * LROW + p);
                float wk8[8];
                *(float4*)&wk8[0] = *(const float4*)&s_ww[k0];
                *(float4*)&wk8[4] = *(const float4*)&s_ww[k0 + 4];
                float l0v[8], l1v[8];
#pragma unroll
                for (int u = 0; u < 8; ++u) {
                    int k = k0 + u;
                    float wk = wk8[u];
                    float2 lf = __half22float2(lv[u]);
                    float l0 = (1.f - wk - wwc0) * lf.x + wk * pt0;
                    float l1 = (1.f - wk - wwc1) * lf.y + wk * pt1;
                    if (k == c0) l0 = 0.f;
                    if (k == c1) l1 = 0.f;
                    l0v[u] = l0; l1v[u] = l1;
                }
#pragma unroll
                for (int u = 0; u < 8; ++u)
                    lwrite((k0 + u) * LROW + p, pkh(l0v[u], l1v[u]));
                __half2 l0p[4], l1p[4];
#pragma unroll
                for (int i = 0; i < 4; ++i) {
                    l0p[i] = pkh(l0v[2*i], l0v[2*i+1]);
                    l1p[i] = pkh(l1v[2*i], l1v[2*i+1]);
                }
                int kp0 = k0 >> 1;
#pragma unroll
                for (int r = 0; r < 4; ++r) {
                    __half2 rp[4];
                    *(float4*)rp = *(const float4*)(s_rwh + r * 128 + kp0);
#pragma unroll
                    for (int i = 0; i < 4; ++i) {
                        acc[r]     = fdot2(l0p[i], rp[i], acc[r]);
                        acc[4 + r] = fdot2(l1p[i], rp[i], acc[4 + r]);
                    }
                }
            }
            __half2* bp = (__half2*)scrh + (kc * 128 + p) * 4;
            bp[0] = pkh(acc[0], acc[1]);
            bp[1] = pkh(acc[2], acc[3]);
            bp[2] = pkh(acc[4], acc[5]);
            bp[3] = pkh(acc[6], acc[7]);
        } else {
            int t0 = tid - 512;
#pragma unroll 1
            for (int jb = 0; jb < 2; ++jb) {
                __half2 mv[8];
#pragma unroll
                for (int j = 0; j < 8; ++j) mv[j] = memh2[t0 + (jb * 8 + j) * 512];
#pragma unroll
                for (int j = 0; j < 8; ++j) {
                    int i2 = t0 + (jb * 8 + j) * 512;
                    int w = i2 >> 7, n2 = i2 & 127;
                    float er = s_er[w];
                    float wvv = s_z[389 + w];
                    float2 mf = __half22float2(mv[j]);
                    float wa = s_ww[2*n2], wb = s_ww[2*n2 + 1];
                    mf.x = mf.x * (1.f - wa * er) + wa * wvv;
                    mf.y = mf.y * (1.f - wb * er) + wb * wvv;
                    memh2[i2] = __floats2half2_rn(mf.x, mf.y);
                }
            }
        }
        __syncthreads();  // B10

        // ---- P8: fwd row pass (fdot2, b128 rp broadcasts) + prec update ----
        {
            int q = tid >> 8, n8 = tid & 255;
            float f[4] = {0.f, 0.f, 0.f, 0.f};
            int base = n8 * LROW + q * 32;
#pragma unroll 1
            for (int j0 = 0; j0 < 32; j0 += 8) {
                __half2 lv[8];
#pragma unroll
                for (int u = 0; u < 8; ++u) lv[u] = lread(base + j0 + u);
#pragma unroll
                for (int r = 0; r < 4; ++r) {
                    __half2 rp[8];
                    *(float4*)&rp[0] = *(const float4*)(s_rwh + r * 128 + q * 32 + j0);
                    *(float4*)&rp[4] = *(const float4*)(s_rwh + r * 128 + q * 32 + j0 + 4);
#pragma unroll
                    for (int u = 0; u < 8; ++u) f[r] = fdot2(lv[u], rp[u], f[r]);
                }
            }
            __half2* fp2 = (__half2*)(scrh + 4096) + (q * 256 + n8) * 2;
            fp2[0] = pkh(f[0], f[1]);
            fp2[1] = pkh(f[2], f[3]);
            if (q == 0) s_prec[n8] = (1.f - s_red[0]) * s_prec[n8] + s_ww[n8];
        }
        __syncthreads();  // B11

        // ---- P9: rc sim + bwd/fwd reduce (no-max softmax: one reduce round) ----
        int rr = tid >> 8, n8c = tid & 255;
        float bwv = 0.f, fwv = 0.f, e_rc = 0.f;
        {
#pragma unroll
            for (int kc = 0; kc < 4; ++kc)
                bwv += __half2float(scrh[(kc * 128 + (n8c >> 1)) * 8 + (n8c & 1) * 4 + rr]);
#pragma unroll
            for (int qq = 0; qq < 4; ++qq)
                fwv += __half2float(scrh[4096 + (qq * 256 + n8c) * 4 + rr]);
            float ssv = 0.f, dv = 0.f;
#pragma unroll 1
            for (int w0 = 0; w0 < 64; w0 += 16) {
                __half hv[16];
#pragma unroll
                for (int u = 0; u < 16; ++u) hv[u] = memh[(w0 + u) * 256 + n8c];
#pragma unroll
                for (int u = 0; u < 16; ++u) {
                    float m = __half2float(hv[u]);
                    ssv = fmaf(m, m, ssv);
                    dv = fmaf(m, s_z[(w0 + u) * 4 + rr], dv);
                }
            }
            float sim = dv / ((sqrtf(ssv) + EPSf) * s_knorm[rr]) * s_rstr[rr];
            e_rc = expf(sim);        // |sim| small (strength-scaled cosine); R11/R13-verified
            float s = wsum(e_rc);
            if (lane == 0) s_red[16 + wv] = s;
        }
        __syncthreads();  // B12
        {
            float sm = (s_red[16+rr*4+0] + s_red[16+rr*4+1]) + (s_red[16+rr*4+2] + s_red[16+rr*4+3]);
            float rc = e_rc / sm;
            float v = bwv * s_rmode[0*4+rr] + rc * s_rmode[1*4+rr] + fwv * s_rmode[2*4+rr];
            s_rw[n8c*4 + rr] = v;
            float pv = __shfl_xor(v, 1, 64);
            if ((n8c & 1) == 0) s_rwh[rr * 128 + (n8c >> 1)] = pkh(v, pv);
        }
        __syncthreads();  // B13

        // ---- P12: rvec partials (pure fdot2: memh rows x s_rwh pairs) ----
        {
            int kc = tid >> 8, o = tid & 255, w = o >> 2, r = o & 3;
            const __half2* mw2 = (const __half2*)(memh + w * 256 + kc * 64);
            const __half2* rw2 = s_rwh + r * 128 + kc * 32;
            float a = 0.f;
#pragma unroll
            for (int c = 0; c < 8; ++c) {
                __half2 mv[4], rv[4];
                *(float4*)mv = *(const float4*)(mw2 + c * 4);
                *(float4*)rv = *(const float4*)(rw2 + c * 4);
#pragma unroll
                for (int u = 0; u < 4; ++u) a = fdot2(mv[u], rv[u], a);
            }
            scr[kc * 256 + o] = a;
        }
        __syncthreads();  // B14

        // ---- P13: rvec reduce -> ctrl pairs + next-x staging ----
        if (tid < 256) {
            float v = (scr[tid] + scr[256+tid]) + (scr[512+tid] + scr[768+tid]);
            float pv = __shfl_xor(v, 1, 64);
            if ((tid & 1) == 0) s_ctrlh[32 + (tid >> 1)] = pkh(v, pv);
        } else if (tid >= 512 && tid < 544) {
            if (t + 1 < Tt) {
                int i = tid - 512;
                float2 xv = *(const float2*)&x[((t + 1) * Bb + b) * INd + 2 * i];
                s_ctrlh[i] = pkh(xv.x, xv.y);
            }
        }
        __syncthreads();  // B15

        // ---- P14: out GEMV partials ----
        {
            int c4 = wv, o4 = lane;
            const __half2* wsrc = (c4 < 8) ? (wp + WOUTOFF + o4 * 4 + c4 * 1024)
                                           : (wp + WMEMOFF + o4 * 4 + (c4 - 8) * 1024);
            const __half2* vsrc = (c4 < 8) ? (s_nnh + c4 * 16)
                                           : (s_ctrlh + 32 + (c4 - 8) * 16);
            scr[c4 * 64 + o4] = gemv_part(wsrc, 256, 16, vsrc);
        }
        __syncthreads();  // B16
        if (tid < 64) {
            float s = 0.f;
#pragma unroll
            for (int g = 0; g < 16; ++g) s += scr[g * 64 + tid];
            out[(t * Bb + b) * OUTd + tid] = s;
        }
        // loop-top barrier covers remaining hazards
    }
}

extern "C" void kernel_launch(void* const* d_in, const int* in_sizes, int n_in,
                              void* d_out, int out_size, void* d_ws, size_t ws_size,
                              hipStream_t stream) {
    const float* x    = (const float*)d_in[0];
    const float* W1   = (const float*)d_in[1];
    const float* b1   = (const float*)d_in[2];
    const float* W2   = (const float*)d_in[3];
    const float* b2   = (const float*)d_in[4];
    const float* Wif  = (const float*)d_in[5];
    const float* bif  = (const float*)d_in[6];
    const float* Wout = (const float*)d_in[7];
    const float* Wmem = (const float*)d_in[8];
    float* out = (float*)d_out;

    // ws: [0, 601600) packed half2 weights; [601600, +512KB) mem fp16; then fallback link.
    char* ws = (char*)d_ws;
    __half2* wp    = (__half2*)ws;
    __half*  memg  = (__half*)(ws + 601600);
    __half2* linkg = (__half2*)(ws + 601600 + 524288);

    convert_weights<<<dim3((WTOT + 255) / 256), dim3(256), 0, stream>>>(W1, W2, Wif, Wout, Wmem, wp);

    hipError_t rc = hipFuncSetAttribute(
        reinterpret_cast<const void*>(&dnc_kernel<true>),
        hipFuncAttributeMaxDynamicSharedMemorySize, SMEM_MAIN);
    if (rc == hipSuccess) {
        dnc_kernel<true><<<dim3(Bb), dim3(1024), SMEM_MAIN, stream>>>(
            x, b1, b2, bif, wp, memg, linkg, out);
    } else {
        dnc_kernel<false><<<dim3(Bb), dim3(1024), SMEM_FB, stream>>>(
            x, b1, b2, bif, wp, memg, linkg, out);
    }
}

// Round 5
// 1880.089 us; speedup vs baseline: 1.5893x; 1.0630x over previous
//
#include <hip/hip_runtime.h>
#include <hip/hip_fp16.h>
#include <math.h>

#define Tt 64
#define Bb 16
#define Nn 256
#define Ww 64
#define Rr 4
#define INd 64
#define OUTd 64
#define IFS 471
#define EPSf 1e-6f

// packed half2 weight layout: quad-of-k2 per column, wave-coalesced.
// index = OFF + ((k2>>2)*Ncol + n)*4 + (k2&3); lane n loads dwordx4 (4 k2-pairs),
// consecutive lanes 16B apart -> 1KiB per wave per load instruction.
#define W1OFF   0        // K2=160, Ncol=256 -> 40960
#define W2OFF   40960    // K2=128, Ncol=256 -> 32768
#define WIFOFF  73728    // K2=128, Ncol=471 -> 60288
#define WOUTOFF 134016   // K2=128, Ncol=64  -> 8192
#define WMEMOFF 142208   // K2=128, Ncol=64  -> 8192
#define WTOT    150400

// link: 256 rows x 129 dwords (258 halfs; 256 used + 2 pad)
#define LROW    129
#define LINKB   (256 * LROW * 4)     // 132096 B
#define SCRB    16384                // 4096 floats / 8192 halfs
#define FIXF    3456
#define SMEM_MAIN (LINKB + SCRB + FIXF * 4)   // 162304 <= 163840
#define SMEM_FB   (SCRB + FIXF * 4)

// s_rwh padded r-stride: 132 dwords (132%32=4 -> r-groups on disjoint banks)
#define RWS 132

typedef _Float16 h2v __attribute__((ext_vector_type(2)));
__device__ __forceinline__ float fdot2(__half2 a, __half2 b, float c) {
    return __builtin_amdgcn_fdot2(*(h2v*)&a, *(h2v*)&b, c, false);
}
__device__ __forceinline__ __half2 pkh(float a, float b) {
    auto r = __builtin_amdgcn_cvt_pkrtz(a, b);   // __fp16 ext_vector(2)
    return *(__half2*)&r;
}

__device__ __forceinline__ float sigm(float x) { return 1.f / (1.f + expf(-x)); }
__device__ __forceinline__ float oneplus_(float x) {
    return 1.f + fmaxf(x, 0.f) + log1pf(expf(-fabsf(x)));
}
__device__ __forceinline__ float wsum(float v) {
#pragma unroll
    for (int o = 32; o; o >>= 1) v += __shfl_xor(v, o, 64);
    return v;
}
__device__ __forceinline__ float wmaxr(float v) {
#pragma unroll
    for (int o = 32; o; o >>= 1) v = fmaxf(v, __shfl_xor(v, o, 64));
    return v;
}

// shared GEMV-partial body. wP = column base (wp + OFF + n*4), str = Ncol*4
// (half2 units per k8 block), iters in k2 units (multiple of 8).
__device__ __attribute__((noinline)) float gemv_part(
    const __half2* __restrict__ wP, int str, int iters,
    const __half2* __restrict__ vin)
{
    float a[8] = {0.f,0.f,0.f,0.f,0.f,0.f,0.f,0.f};
#pragma unroll 1
    for (int j0 = 0; j0 < iters; j0 += 8) {
        __half2 hh[8], vv[8];
        int k8 = j0 >> 2;
        *(float4*)&hh[0] = *(const float4*)(wP + (size_t)k8 * str);
        *(float4*)&hh[4] = *(const float4*)(wP + (size_t)(k8 + 1) * str);
        *(float4*)&vv[0] = *(const float4*)(vin + j0);
        *(float4*)&vv[4] = *(const float4*)(vin + j0 + 4);
#pragma unroll
        for (int u = 0; u < 8; ++u) a[u] = fdot2(hh[u], vv[u], a[u]);
    }
    return ((a[0]+a[1])+(a[2]+a[3])) + ((a[4]+a[5])+(a[6]+a[7]));
}

// ---- converter: fp32 weights -> packed half2 quad layout ----
__global__ void convert_weights(const float* __restrict__ W1, const float* __restrict__ W2,
                                const float* __restrict__ Wif, const float* __restrict__ Wout,
                                const float* __restrict__ Wmem, __half2* __restrict__ wp) {
    int i = blockIdx.x * blockDim.x + threadIdx.x;
    if (i >= WTOT) return;
    float a, b;
    if (i < W2OFF) {
        int q = i & 3, s = i >> 2, n = s & 255, k2 = (s >> 8) * 4 + q;
        a = W1[(2*k2)*256+n];  b = W1[(2*k2+1)*256+n];
    } else if (i < WIFOFF) {
        int t = i - W2OFF;
        int q = t & 3, s = t >> 2, n = s & 255, k2 = (s >> 8) * 4 + q;
        a = W2[(2*k2)*256+n];  b = W2[(2*k2+1)*256+n];
    } else if (i < WOUTOFF) {
        int t = i - WIFOFF;
        int q = t & 3, s = t >> 2, o = s % IFS, k2 = (s / IFS) * 4 + q;
        a = Wif[(2*k2)*IFS+o]; b = Wif[(2*k2+1)*IFS+o];
    } else if (i < WMEMOFF) {
        int t = i - WOUTOFF;
        int q = t & 3, s = t >> 2, n = s & 63, k2 = (s >> 6) * 4 + q;
        a = Wout[(2*k2)*64+n]; b = Wout[(2*k2+1)*64+n];
    } else {
        int t = i - WMEMOFF;
        int q = t & 3, s = t >> 2, n = s & 63, k2 = (s >> 6) * 4 + q;
        a = Wmem[(2*k2)*64+n]; b = Wmem[(2*k2+1)*64+n];
    }
    wp[i] = __floats2half2_rn(a, b);
}

template <bool LLINK>
__global__ __launch_bounds__(1024) void dnc_kernel(
    const float* __restrict__ x, const float* __restrict__ b1,
    const float* __restrict__ b2, const float* __restrict__ bif,
    const __half2* __restrict__ wp,
    __half* __restrict__ memg,      // per batch 64*256 halves, [w][n]
    __half2* __restrict__ memWg,    // per batch 32*256 dwords, [w2][n] = (m[2w2][n], m[2w2+1][n])
    __half2* __restrict__ linkg,    // fallback link
    float* __restrict__ out)
{
    extern __shared__ __align__(16) char smem[];
    const int b = blockIdx.x;
    const int tid = threadIdx.x;
    const int lane = tid & 63;
    const int wv = tid >> 6;

    __half2* l2p = (__half2*)smem;
    __half2* gl2 = linkg + (size_t)b * (256 * LROW);
    float* scr   = (float*)(smem + (LLINK ? LINKB : 0));
    __half* scrh = (__half*)scr;
    float* fx    = (float*)((char*)scr + SCRB);

    float*   s_rw    = fx + 0;                    // 1024 [n][r] fp32
    __half2* s_ctrlh = (__half2*)(fx + 1024);     // 160: [0,32) x pairs, [32,160) rvec pairs
    __half2* s_hh    = (__half2*)(fx + 1184);     // 128
    __half2* s_nnh   = (__half2*)(fx + 1312);     // 128
    __half2* s_rwh   = (__half2*)(fx + 1440);     // 528 = [r][RWS n-pairs], 128 used per r
    float* s_z     = fx + 1968;   // 472
    float* s_usage = fx + 2440;   // 256
    float* s_ww    = fx + 2696;   // 256
    float* s_prec  = fx + 2952;   // 256
    float* s_knorm = fx + 3208;   // 4
    float* s_rstr  = fx + 3212;   // 4
    float* s_rmode = fx + 3216;   // 12
    float* s_sc    = fx + 3228;   // 4
    float* s_red   = fx + 3232;   // 32
    float* s_er    = fx + 3264;   // 64 (erase gates, precomputed)
    __half2* s_keyh = (__half2*)(fx + 3328);      // 128 [r][32 w2] read-key pairs -> 3456 = FIXF
    float* s_srt   = scr + 1024;  // 256 (mega only, B8..B9)
    float* s_cp    = scr + 1280;  // 256 (mega only, B8..B9)
    __half2* s_keyw2 = (__half2*)(scr + 1280);    // 32 write-key pairs (B5..B7 lifetime; dead before cp)
    float* s_wcdot = scr + 1536;  // 256 (B6..B9 lifetime)
    float* s_wcss  = scr + 1792;  // 256 (B6..B9 lifetime)

    __half*  memh  = memg + (size_t)b * (Ww * Nn);
    __half2* memh2 = (__half2*)memh;
    __half2* memW2 = memWg + (size_t)b * (32 * 256);
    __half*  memWh = (__half*)memW2;

    auto lread = [&](int idx) -> __half2 {
        if constexpr (LLINK) return l2p[idx]; else return gl2[idx];
    };
    auto lwrite = [&](int idx, __half2 v) {
        if constexpr (LLINK) l2p[idx] = v; else gl2[idx] = v;
    };

    // ---- init (ws/LDS poisoned before every launch) ----
    {
        __half2 z2 = pkh(0.f, 0.f);
#pragma unroll 1
        for (int i = tid; i < 256 * LROW; i += 1024) lwrite(i, z2);
        __half2 e2 = __floats2half2_rn(EPSf, EPSf);
#pragma unroll 1
        for (int j = 0; j < 8; ++j) { memh2[tid + j * 1024] = e2; memW2[tid + j * 1024] = e2; }
        if (tid < 528) s_rwh[tid] = z2;
        if (tid < 32) {
            float2 xv = *(const float2*)&x[b * INd + 2 * tid];
            s_ctrlh[tid] = pkh(xv.x, xv.y);
        } else if (tid < 160) s_ctrlh[tid] = z2;
    }
    if (tid < 256) {
        s_usage[tid] = 0.f; s_ww[tid] = 0.f; s_prec[tid] = 0.f;
        s_rw[tid*4+0] = 0.f; s_rw[tid*4+1] = 0.f; s_rw[tid*4+2] = 0.f; s_rw[tid*4+3] = 0.f;
    }

#pragma unroll 1
    for (int t = 0; t < Tt; ++t) {
        __syncthreads();  // B0

        // ---- P1: GEMV1 partials ----
        {
            int kc = wv >> 2, o = (wv & 3) * 64 + lane;
            scr[kc * 256 + o] = gemv_part(wp + W1OFF + o * 4 + kc * 10240, 1024, 40,
                                          s_ctrlh + kc * 40);
        }
        __syncthreads();  // B1
        if (tid < 256) {
            float v = tanhf(b1[tid] + ((scr[tid] + scr[256+tid]) + (scr[512+tid] + scr[768+tid])));
            float pv = __shfl_xor(v, 1, 64);
            if ((tid & 1) == 0) s_hh[tid >> 1] = pkh(v, pv);
        }
        __syncthreads();  // B2

        // ---- P2: GEMV2 partials ----
        {
            int kc = wv >> 2, o = (wv & 3) * 64 + lane;
            scr[kc * 256 + o] = gemv_part(wp + W2OFF + o * 4 + kc * 8192, 1024, 32,
                                          s_hh + kc * 32);
        }
        __syncthreads();  // B3
        if (tid < 256) {
            float v = tanhf(b2[tid] + ((scr[tid] + scr[256+tid]) + (scr[512+tid] + scr[768+tid])));
            float pv = __shfl_xor(v, 1, 64);
            if ((tid & 1) == 0) s_nnh[tid >> 1] = pkh(v, pv);
        }
        __syncthreads();  // B4

        // ---- P3: GEMV3 partials ----
        {
            int kc = wv >> 3, o = (wv & 7) * 64 + lane;
            if (o < IFS)
                scr[kc * 512 + o] = gemv_part(wp + WIFOFF + o * 4 + kc * 30144, 1884, 64,
                                              s_nnh + kc * 64);
        }
        __syncthreads();  // B5
        // s_z + packed key copies.
        // read keys: key[w][r] = z[w*4+r]; pair over (w, w+1) -> (z[8w2+r], z[8w2+4+r]).
        // write key: wkey[w] = z[260+w]; pair (2i, 2i+1).
        if (tid < IFS) {
            float v = bif[tid] + scr[tid] + scr[512 + tid];
            s_z[tid] = v;
            float pv1 = __shfl_xor(v, 1, 64);   // hoisted: all lanes of waves 0-7 participate
            float pv4 = __shfl_xor(v, 4, 64);
            if (tid < 256) {
                if ((tid & 4) == 0)             // w even
                    s_keyh[(tid & 3) * 32 + (tid >> 3)] = pkh(v, pv4);
            } else if (tid >= 260 && tid < 324) {
                if ((tid & 1) == 0)
                    s_keyw2[(tid - 260) >> 1] = pkh(v, pv1);
            }
        }
        __syncthreads();  // B6

        // ---- P4: scalars + usage + wc dot/ss (merged wave roles) ----
        if (wv < 4) {
            float vz = s_z[lane * 4 + wv];
            float s = wsum(vz * vz);
            if (lane == 0) s_knorm[wv] = sqrtf(s) + EPSf;
        } else if (wv == 4) {
            float vz = s_z[260 + lane];
            float s = wsum(vz * vz);
            if (lane == 0) s_sc[3] = sqrtf(s) + EPSf;
        } else if (wv == 5) {
            if (lane < 4) s_rstr[lane] = oneplus_(s_z[256 + lane]);
            else if (lane >= 8 && lane < 12) {
                int r = lane - 8;
                float a = s_z[459+r], bm = s_z[463+r], c = s_z[467+r];
                float mx = fmaxf(a, fmaxf(bm, c));
                float ea = expf(a-mx), eb = expf(bm-mx), ec = expf(c-mx);
                float inv = 1.f / ((ea+eb)+ec);
                s_rmode[0*4+r] = ea*inv; s_rmode[1*4+r] = eb*inv; s_rmode[2*4+r] = ec*inv;
            } else if (lane == 16) s_sc[0] = oneplus_(s_z[324]);
            else if (lane == 17) s_sc[1] = sigm(s_z[457]);
            else if (lane == 18) s_sc[2] = sigm(s_z[458]);
        } else if (wv == 6) {
            s_er[lane] = sigm(s_z[325 + lane]);   // erase gates, once per step
        } else if (wv >= 8 && wv < 12) {
            int n = tid - 512;
            float ret = 1.f;
#pragma unroll
            for (int r = 0; r < 4; ++r) {
                float fg = sigm(s_z[453 + r]);
                ret *= 1.f - fg * s_rw[n*4 + r];
            }
            float u = s_usage[n], wwo = s_ww[n];
            s_usage[n] = (u + wwo - u * wwo) * ret;
        } else if (wv >= 12) {
            // wc dot/ss via memW (old mem, coalesced dword columns, pure fdot2)
            int n = tid - 768;
            const __half2* mW = memW2 + n;
            float dot = 0.f, ssv = 0.f;
#pragma unroll 1
            for (int c = 0; c < 32; c += 8) {
                __half2 mv[8], kv[8];
#pragma unroll
                for (int u = 0; u < 8; ++u) mv[u] = mW[(c + u) * 256];
                *(float4*)&kv[0] = *(const float4*)(s_keyw2 + c);
                *(float4*)&kv[4] = *(const float4*)(s_keyw2 + c + 4);
#pragma unroll
                for (int u = 0; u < 8; ++u) {
                    ssv = fdot2(mv[u], mv[u], ssv);
                    dot = fdot2(mv[u], kv[u], dot);
                }
            }
            s_wcdot[n] = dot; s_wcss[n] = ssv;
        }
        __syncthreads();  // B7

        // ---- P5: rank partials (float4 broadcast reads of usage) ----
        {
            int q = tid >> 8, n = tid & 255;
            float un = s_usage[n];
            float cnt = 0.f;
            int j0 = q * 64;
#pragma unroll 1
            for (int j = j0; j < j0 + 64; j += 4) {
                float4 uv = *(const float4*)&s_usage[j];
                cnt += (uv.x < un || (uv.x == un && j     < n)) ? 1.f : 0.f;
                cnt += (uv.y < un || (uv.y == un && j + 1 < n)) ? 1.f : 0.f;
                cnt += (uv.z < un || (uv.z == un && j + 2 < n)) ? 1.f : 0.f;
                cnt += (uv.w < un || (uv.w == un && j + 3 < n)) ? 1.f : 0.f;
            }
            scr[q * 256 + n] = cnt;
        }
        __syncthreads();  // B8

        // ---- P6: mega (wave 0) ----
        if (wv == 0) {
            int rk[4]; float uu[4];
#pragma unroll
            for (int i = 0; i < 4; ++i) {
                int n = lane * 4 + i;
                float c = scr[n] + scr[256+n] + scr[512+n] + scr[768+n];
                rk[i] = (int)(c + 0.5f);
                uu[i] = s_usage[n];
                s_srt[rk[i]] = uu[i];
            }
            float4 vs = ((const float4*)s_srt)[lane];
            float p1 = vs.x * vs.y, p2 = p1 * vs.z, tot = p2 * vs.w;
            float incl = tot;
#pragma unroll
            for (int off = 1; off < 64; off <<= 1) {
                float tv = __shfl_up(incl, off, 64);
                if (lane >= off) incl *= tv;
            }
            float excl = __shfl_up(incl, 1, 64);
            if (lane == 0) excl = 1.f;
            float4 o4v; o4v.x = excl; o4v.y = excl*vs.x; o4v.z = excl*p1; o4v.w = excl*p2;
            ((float4*)s_cp)[lane] = o4v;

            float sims[4], mx = -1e30f;
#pragma unroll
            for (int i = 0; i < 4; ++i) {
                int n = lane * 4 + i;
                sims[i] = s_wcdot[n] / ((sqrtf(s_wcss[n]) + EPSf) * s_sc[3]) * s_sc[0];
                mx = fmaxf(mx, sims[i]);
            }
            mx = wmaxr(mx);
            float es[4], ls = 0.f;
#pragma unroll
            for (int i = 0; i < 4; ++i) { es[i] = expf(sims[i] - mx); ls += es[i]; }
            ls = wsum(ls);
            float ag = s_sc[1], wg = s_sc[2], inv = 1.f / ls, lw = 0.f;
#pragma unroll
            for (int i = 0; i < 4; ++i) {
                int n = lane * 4 + i;
                float alloc = (1.f - uu[i]) * s_cp[rk[i]];
                float wwn = wg * (ag * alloc + (1.f - ag) * es[i] * inv);
                s_ww[n] = wwn; lw += wwn;
            }
            lw = wsum(lw);
            if (lane == 0) s_red[0] = lw;
        }
        __syncthreads();  // B9

        // ---- P7: link col pass (8 waves; bwd via fdot2) || mem RMW (8 waves) ----
        if (tid < 512) {
            int kc = tid >> 7, p = tid & 127;
            int c0 = 2 * p, c1 = c0 + 1;
            float wwc0 = s_ww[c0], wwc1 = s_ww[c1];
            float pt0 = s_prec[c0], pt1 = s_prec[c1];
            float acc[8] = {0,0,0,0,0,0,0,0};
            int kbase = kc * 64;
#pragma unroll 1
            for (int k0 = kbase; k0 < kbase + 64; k0 += 8) {
                __half2 lv[8];
#pragma unroll
                for (int u = 0; u < 8; ++u) lv[u] = lread((k0 + u) * LROW + p);
                float wk8[8];
                *(float4*)&wk8[0] = *(const float4*)&s_ww[k0];
                *(float4*)&wk8[4] = *(const float4*)&s_ww[k0 + 4];
                float l0v[8], l1v[8];
#pragma unroll
                for (int u = 0; u < 8; ++u) {
                    int k = k0 + u;
                    float wk = wk8[u];
                    float2 lf = __half22float2(lv[u]);
                    float l0 = (1.f - wk - wwc0) * lf.x + wk * pt0;
                    float l1 = (1.f - wk - wwc1) * lf.y + wk * pt1;
                    if (k == c0) l0 = 0.f;
                    if (k == c1) l1 = 0.f;
                    l0v[u] = l0; l1v[u] = l1;
                }
#pragma unroll
                for (int u = 0; u < 8; ++u)
                    lwrite((k0 + u) * LROW + p, pkh(l0v[u], l1v[u]));
                __half2 l0p[4], l1p[4];
#pragma unroll
                for (int i = 0; i < 4; ++i) {
                    l0p[i] = pkh(l0v[2*i], l0v[2*i+1]);
                    l1p[i] = pkh(l1v[2*i], l1v[2*i+1]);
                }
                int kp0 = k0 >> 1;
#pragma unroll
                for (int r = 0; r < 4; ++r) {
                    __half2 rp[4];
                    *(float4*)rp = *(const float4*)(s_rwh + r * RWS + kp0);
#pragma unroll
                    for (int i = 0; i < 4; ++i) {
                        acc[r]     = fdot2(l0p[i], rp[i], acc[r]);
                        acc[4 + r] = fdot2(l1p[i], rp[i], acc[4 + r]);
                    }
                }
            }
            __half2* bp = (__half2*)scrh + (kc * 128 + p) * 4;
            bp[0] = pkh(acc[0], acc[1]);
            bp[1] = pkh(acc[2], acc[3]);
            bp[2] = pkh(acc[4], acc[5]);
            bp[3] = pkh(acc[6], acc[7]);
        } else {
            int t0 = tid - 512;
#pragma unroll 1
            for (int jb = 0; jb < 2; ++jb) {
                __half2 mv[8];
#pragma unroll
                for (int j = 0; j < 8; ++j) mv[j] = memh2[t0 + (jb * 8 + j) * 512];
#pragma unroll
                for (int j = 0; j < 8; ++j) {
                    int i2 = t0 + (jb * 8 + j) * 512;
                    int w = i2 >> 7, n2 = i2 & 127;
                    float er = s_er[w];
                    float wvv = s_z[389 + w];
                    float2 mf = __half22float2(mv[j]);
                    float wa = s_ww[2*n2], wb = s_ww[2*n2 + 1];
                    mf.x = mf.x * (1.f - wa * er) + wa * wvv;
                    mf.y = mf.y * (1.f - wb * er) + wb * wvv;
                    __half2 hv = __floats2half2_rn(mf.x, mf.y);
                    memh2[i2] = hv;
                    // keep w-pair copy in sync: memW[(w>>1)*256 + n] halves (w&1)
                    int wb2 = (w >> 1) * 512 + 4 * n2 + (w & 1);
                    memWh[wb2]     = __low2half(hv);    // n = 2*n2
                    memWh[wb2 + 2] = __high2half(hv);   // n = 2*n2+1
                }
            }
        }
        __syncthreads();  // B10

        // ---- P8: fwd row pass (fdot2, b128 rp broadcasts) + prec update ----
        {
            int q = tid >> 8, n8 = tid & 255;
            float f[4] = {0.f, 0.f, 0.f, 0.f};
            int base = n8 * LROW + q * 32;
#pragma unroll 1
            for (int j0 = 0; j0 < 32; j0 += 8) {
                __half2 lv[8];
#pragma unroll
                for (int u = 0; u < 8; ++u) lv[u] = lread(base + j0 + u);
#pragma unroll
                for (int r = 0; r < 4; ++r) {
                    __half2 rp[8];
                    *(float4*)&rp[0] = *(const float4*)(s_rwh + r * RWS + q * 32 + j0);
                    *(float4*)&rp[4] = *(const float4*)(s_rwh + r * RWS + q * 32 + j0 + 4);
#pragma unroll
                    for (int u = 0; u < 8; ++u) f[r] = fdot2(lv[u], rp[u], f[r]);
                }
            }
            __half2* fp2 = (__half2*)(scrh + 4096) + (q * 256 + n8) * 2;
            fp2[0] = pkh(f[0], f[1]);
            fp2[1] = pkh(f[2], f[3]);
            if (q == 0) s_prec[n8] = (1.f - s_red[0]) * s_prec[n8] + s_ww[n8];
        }
        __syncthreads();  // B11

        // ---- P9: rc sim via memW (new mem, fdot2) + bwd/fwd reduce ----
        int rr = tid >> 8, n8c = tid & 255;
        float bwv = 0.f, fwv = 0.f, e_rc = 0.f;
        {
#pragma unroll
            for (int kc = 0; kc < 4; ++kc)
                bwv += __half2float(scrh[(kc * 128 + (n8c >> 1)) * 8 + (n8c & 1) * 4 + rr]);
#pragma unroll
            for (int qq = 0; qq < 4; ++qq)
                fwv += __half2float(scrh[4096 + (qq * 256 + n8c) * 4 + rr]);
            const __half2* mW = memW2 + n8c;
            const __half2* kh = s_keyh + rr * 32;
            float ssv = 0.f, dv = 0.f;
#pragma unroll 1
            for (int c = 0; c < 32; c += 8) {
                __half2 mv[8], kv[8];
#pragma unroll
                for (int u = 0; u < 8; ++u) mv[u] = mW[(c + u) * 256];
                *(float4*)&kv[0] = *(const float4*)(kh + c);
                *(float4*)&kv[4] = *(const float4*)(kh + c + 4);
#pragma unroll
                for (int u = 0; u < 8; ++u) {
                    ssv = fdot2(mv[u], mv[u], ssv);
                    dv  = fdot2(mv[u], kv[u], dv);
                }
            }
            float sim = dv / ((sqrtf(ssv) + EPSf) * s_knorm[rr]) * s_rstr[rr];
            e_rc = expf(sim);        // |sim| small (strength-scaled cosine); R11/R13-verified
            float s = wsum(e_rc);
            if (lane == 0) s_red[16 + wv] = s;
        }
        __syncthreads();  // B12
        {
            float sm = (s_red[16+rr*4+0] + s_red[16+rr*4+1]) + (s_red[16+rr*4+2] + s_red[16+rr*4+3]);
            float rc = e_rc / sm;
            float v = bwv * s_rmode[0*4+rr] + rc * s_rmode[1*4+rr] + fwv * s_rmode[2*4+rr];
            s_rw[n8c*4 + rr] = v;
            float pv = __shfl_xor(v, 1, 64);
            if ((n8c & 1) == 0) s_rwh[rr * RWS + (n8c >> 1)] = pkh(v, pv);
        }
        __syncthreads();  // B13

        // ---- P12: rvec partials (pure fdot2: memh rows x s_rwh pairs) ----
        {
            int kc = tid >> 8, o = tid & 255, w = o >> 2, r = o & 3;
            const __half2* mw2 = (const __half2*)(memh + w * 256 + kc * 64);
            const __half2* rw2 = s_rwh + r * RWS + kc * 32;
            float a = 0.f;
#pragma unroll
            for (int c = 0; c < 8; ++c) {
                __half2 mv[4], rv[4];
                *(float4*)mv = *(const float4*)(mw2 + c * 4);
                *(float4*)rv = *(const float4*)(rw2 + c * 4);
#pragma unroll
                for (int u = 0; u < 4; ++u) a = fdot2(mv[u], rv[u], a);
            }
            scr[kc * 256 + o] = a;
        }
        __syncthreads();  // B14

        // ---- P13: rvec reduce -> ctrl pairs + next-x staging ----
        if (tid < 256) {
            float v = (scr[tid] + scr[256+tid]) + (scr[512+tid] + scr[768+tid]);
            float pv = __shfl_xor(v, 1, 64);
            if ((tid & 1) == 0) s_ctrlh[32 + (tid >> 1)] = pkh(v, pv);
        } else if (tid >= 512 && tid < 544) {
            if (t + 1 < Tt) {
                int i = tid - 512;
                float2 xv = *(const float2*)&x[((t + 1) * Bb + b) * INd + 2 * i];
                s_ctrlh[i] = pkh(xv.x, xv.y);
            }
        }
        __syncthreads();  // B15

        // ---- P14: out GEMV partials ----
        {
            int c4 = wv, o4 = lane;
            const __half2* wsrc = (c4 < 8) ? (wp + WOUTOFF + o4 * 4 + c4 * 1024)
                                           : (wp + WMEMOFF + o4 * 4 + (c4 - 8) * 1024);
            const __half2* vsrc = (c4 < 8) ? (s_nnh + c4 * 16)
                                           : (s_ctrlh + 32 + (c4 - 8) * 16);
            scr[c4 * 64 + o4] = gemv_part(wsrc, 256, 16, vsrc);
        }
        __syncthreads();  // B16
        if (tid < 64) {
            float s = 0.f;
#pragma unroll
            for (int g = 0; g < 16; ++g) s += scr[g * 64 + tid];
            out[(t * Bb + b) * OUTd + tid] = s;
        }
        // loop-top barrier covers remaining hazards
    }
}

extern "C" void kernel_launch(void* const* d_in, const int* in_sizes, int n_in,
                              void* d_out, int out_size, void* d_ws, size_t ws_size,
                              hipStream_t stream) {
    const float* x    = (const float*)d_in[0];
    const float* W1   = (const float*)d_in[1];
    const float* b1   = (const float*)d_in[2];
    const float* W2   = (const float*)d_in[3];
    const float* b2   = (const float*)d_in[4];
    const float* Wif  = (const float*)d_in[5];
    const float* bif  = (const float*)d_in[6];
    const float* Wout = (const float*)d_in[7];
    const float* Wmem = (const float*)d_in[8];
    float* out = (float*)d_out;

    // ws: [0, 601600) packed half2 weights; [601600, +512KB) mem fp16 [w][n];
    // then memW [w2][n] pair copy (512KB); then fallback link.
    char* ws = (char*)d_ws;
    __half2* wp    = (__half2*)ws;
    __half*  memg  = (__half*)(ws + 601600);
    __half2* memWg = (__half2*)(ws + 601600 + 524288);
    __half2* linkg = (__half2*)(ws + 601600 + 524288 + 524288);

    convert_weights<<<dim3((WTOT + 255) / 256), dim3(256), 0, stream>>>(W1, W2, Wif, Wout, Wmem, wp);

    hipError_t rc = hipFuncSetAttribute(
        reinterpret_cast<const void*>(&dnc_kernel<true>),
        hipFuncAttributeMaxDynamicSharedMemorySize, SMEM_MAIN);
    if (rc == hipSuccess) {
        dnc_kernel<true><<<dim3(Bb), dim3(1024), SMEM_MAIN, stream>>>(
            x, b1, b2, bif, wp, memg, memWg, linkg, out);
    } else {
        dnc_kernel<false><<<dim3(Bb), dim3(1024), SMEM_FB, stream>>>(
            x, b1, b2, bif, wp, memg, memWg, linkg, out);
    }
}

// Round 6
// 1836.580 us; speedup vs baseline: 1.6269x; 1.0237x over previous
//
#include <hip/hip_runtime.h>
#include <hip/hip_fp16.h>
#include <math.h>

#define Tt 64
#define Bb 16
#define Nn 256
#define Ww 64
#define Rr 4
#define INd 64
#define OUTd 64
#define IFS 471
#define EPSf 1e-6f

// packed half2 weight layout: quad-of-k2 per column, wave-coalesced.
// index = OFF + ((k2>>2)*Ncol + n)*4 + (k2&3); lane n loads dwordx4 (4 k2-pairs),
// consecutive lanes 16B apart -> 1KiB per wave per load instruction.
#define W1OFF   0        // K2=160, Ncol=256 -> 40960
#define W2OFF   40960    // K2=128, Ncol=256 -> 32768
#define WIFOFF  73728    // K2=128, Ncol=471 -> 60288
#define WOUTOFF 134016   // K2=128, Ncol=64  -> 8192
#define WMEMOFF 142208   // K2=128, Ncol=64  -> 8192
#define WTOT    150400

// link: 256 rows x 129 dwords (258 halfs; 256 used + 2 pad)
#define LROW    129
#define LINKB   (256 * LROW * 4)     // 132096 B
#define SCRB    16384                // 4096 floats / 8192 halfs
#define FIXF    3456
#define SMEM_MAIN (LINKB + SCRB + FIXF * 4)   // 162304 <= 163840
#define SMEM_FB   (SCRB + FIXF * 4)

// s_rwh padded r-stride: 132 dwords (132%32=4 -> r-groups on disjoint banks)
#define RWS 132

typedef _Float16 h2v __attribute__((ext_vector_type(2)));
__device__ __forceinline__ float fdot2(__half2 a, __half2 b, float c) {
    return __builtin_amdgcn_fdot2(*(h2v*)&a, *(h2v*)&b, c, false);
}
__device__ __forceinline__ __half2 pkh(float a, float b) {
    auto r = __builtin_amdgcn_cvt_pkrtz(a, b);   // __fp16 ext_vector(2)
    return *(__half2*)&r;
}

__device__ __forceinline__ float sigm(float x) { return 1.f / (1.f + expf(-x)); }
__device__ __forceinline__ float oneplus_(float x) {
    return 1.f + fmaxf(x, 0.f) + log1pf(expf(-fabsf(x)));
}
__device__ __forceinline__ float wsum(float v) {
#pragma unroll
    for (int o = 32; o; o >>= 1) v += __shfl_xor(v, o, 64);
    return v;
}
__device__ __forceinline__ float wmaxr(float v) {
#pragma unroll
    for (int o = 32; o; o >>= 1) v = fmaxf(v, __shfl_xor(v, o, 64));
    return v;
}

// shared GEMV-partial body. wP = column base (wp + OFF + n*4), str = Ncol*4
// (half2 units per k8 block), iters in k2 units (multiple of 8, >= 16).
// Weight dwordx4 loads double-buffered one chunk ahead so the ~300cy
// L2/L3 latency overlaps the current chunk's fdot2s.
__device__ __attribute__((noinline)) float gemv_part(
    const __half2* __restrict__ wP, int str, int iters,
    const __half2* __restrict__ vin)
{
    float a[8] = {0.f,0.f,0.f,0.f,0.f,0.f,0.f,0.f};
    float4 h0 = *(const float4*)(wP);
    float4 h1 = *(const float4*)(wP + str);
#pragma unroll 1
    for (int j0 = 0; j0 < iters - 8; j0 += 8) {
        int k8n = (j0 >> 2) + 2;
        float4 n0 = *(const float4*)(wP + (size_t)k8n * str);
        float4 n1 = *(const float4*)(wP + (size_t)(k8n + 1) * str);
        float4 v0 = *(const float4*)(vin + j0);
        float4 v1 = *(const float4*)(vin + j0 + 4);
        const __half2* hh0 = (const __half2*)&h0;
        const __half2* hh1 = (const __half2*)&h1;
        const __half2* vv0 = (const __half2*)&v0;
        const __half2* vv1 = (const __half2*)&v1;
#pragma unroll
        for (int u = 0; u < 4; ++u) a[u]     = fdot2(hh0[u], vv0[u], a[u]);
#pragma unroll
        for (int u = 0; u < 4; ++u) a[4 + u] = fdot2(hh1[u], vv1[u], a[4 + u]);
        h0 = n0; h1 = n1;
    }
    {
        float4 v0 = *(const float4*)(vin + iters - 8);
        float4 v1 = *(const float4*)(vin + iters - 4);
        const __half2* hh0 = (const __half2*)&h0;
        const __half2* hh1 = (const __half2*)&h1;
        const __half2* vv0 = (const __half2*)&v0;
        const __half2* vv1 = (const __half2*)&v1;
#pragma unroll
        for (int u = 0; u < 4; ++u) a[u]     = fdot2(hh0[u], vv0[u], a[u]);
#pragma unroll
        for (int u = 0; u < 4; ++u) a[4 + u] = fdot2(hh1[u], vv1[u], a[4 + u]);
    }
    return ((a[0]+a[1])+(a[2]+a[3])) + ((a[4]+a[5])+(a[6]+a[7]));
}

// ---- converter: fp32 weights -> packed half2 quad layout ----
__global__ void convert_weights(const float* __restrict__ W1, const float* __restrict__ W2,
                                const float* __restrict__ Wif, const float* __restrict__ Wout,
                                const float* __restrict__ Wmem, __half2* __restrict__ wp) {
    int i = blockIdx.x * blockDim.x + threadIdx.x;
    if (i >= WTOT) return;
    float a, b;
    if (i < W2OFF) {
        int q = i & 3, s = i >> 2, n = s & 255, k2 = (s >> 8) * 4 + q;
        a = W1[(2*k2)*256+n];  b = W1[(2*k2+1)*256+n];
    } else if (i < WIFOFF) {
        int t = i - W2OFF;
        int q = t & 3, s = t >> 2, n = s & 255, k2 = (s >> 8) * 4 + q;
        a = W2[(2*k2)*256+n];  b = W2[(2*k2+1)*256+n];
    } else if (i < WOUTOFF) {
        int t = i - WIFOFF;
        int q = t & 3, s = t >> 2, o = s % IFS, k2 = (s / IFS) * 4 + q;
        a = Wif[(2*k2)*IFS+o]; b = Wif[(2*k2+1)*IFS+o];
    } else if (i < WMEMOFF) {
        int t = i - WOUTOFF;
        int q = t & 3, s = t >> 2, n = s & 63, k2 = (s >> 6) * 4 + q;
        a = Wout[(2*k2)*64+n]; b = Wout[(2*k2+1)*64+n];
    } else {
        int t = i - WMEMOFF;
        int q = t & 3, s = t >> 2, n = s & 63, k2 = (s >> 6) * 4 + q;
        a = Wmem[(2*k2)*64+n]; b = Wmem[(2*k2+1)*64+n];
    }
    wp[i] = __floats2half2_rn(a, b);
}

template <bool LLINK>
__global__ __launch_bounds__(1024) void dnc_kernel(
    const float* __restrict__ x, const float* __restrict__ b1,
    const float* __restrict__ b2, const float* __restrict__ bif,
    const __half2* __restrict__ wp,
    __half* __restrict__ memg,      // per batch 64*256 halves, [w][n]
    __half2* __restrict__ memWg,    // per batch 32*256 dwords, [w2][n] = (m[2w2][n], m[2w2+1][n])
    __half2* __restrict__ linkg,    // fallback link
    float* __restrict__ out)
{
    extern __shared__ __align__(16) char smem[];
    const int b = blockIdx.x;
    const int tid = threadIdx.x;
    const int lane = tid & 63;
    const int wv = tid >> 6;

    __half2* l2p = (__half2*)smem;
    __half2* gl2 = linkg + (size_t)b * (256 * LROW);
    float* scr   = (float*)(smem + (LLINK ? LINKB : 0));
    __half* scrh = (__half*)scr;
    float* fx    = (float*)((char*)scr + SCRB);

    float*   s_rw    = fx + 0;                    // 1024 [n][r] fp32
    __half2* s_ctrlh = (__half2*)(fx + 1024);     // 160: [0,32) x pairs, [32,160) rvec pairs
    __half2* s_hh    = (__half2*)(fx + 1184);     // 128
    __half2* s_nnh   = (__half2*)(fx + 1312);     // 128
    __half2* s_rwh   = (__half2*)(fx + 1440);     // 528 = [r][RWS n-pairs], 128 used per r
    float* s_z     = fx + 1968;   // 472
    float* s_usage = fx + 2440;   // 256
    float* s_ww    = fx + 2696;   // 256
    float* s_prec  = fx + 2952;   // 256
    float* s_knorm = fx + 3208;   // 4
    float* s_rstr  = fx + 3212;   // 4
    float* s_rmode = fx + 3216;   // 12
    float* s_sc    = fx + 3228;   // 4
    float* s_red   = fx + 3232;   // 32
    float* s_er    = fx + 3264;   // 64 (erase gates, precomputed)
    __half2* s_keyh = (__half2*)(fx + 3328);      // 128 [r][32 w2] read-key pairs -> 3456 = FIXF
    float* s_srt   = scr + 1024;  // 256 (mega only, B8..B9)
    float* s_cp    = scr + 1280;  // 256 (mega only, B8..B9)
    __half2* s_keyw2 = (__half2*)(scr + 1280);    // 32 write-key pairs (B5..B7 lifetime; dead before cp)
    float* s_wcdot = scr + 1536;  // 256 (B6..B9 lifetime)
    float* s_wcss  = scr + 1792;  // 256 (B6..B9 lifetime)
    __half2* s_wwh2 = (__half2*)(scr + 2048);     // 256 dup (ww,ww)   (B8..B10 lifetime)
    __half2* s_tmh2 = (__half2*)(scr + 2304);     // 256 dup (1-ww,1-ww)

    __half*  memh  = memg + (size_t)b * (Ww * Nn);
    __half2* memh2 = (__half2*)memh;
    __half2* memW2 = memWg + (size_t)b * (32 * 256);
    __half*  memWh = (__half*)memW2;

    auto lread = [&](int idx) -> __half2 {
        if constexpr (LLINK) return l2p[idx]; else return gl2[idx];
    };
    auto lwrite = [&](int idx, __half2 v) {
        if constexpr (LLINK) l2p[idx] = v; else gl2[idx] = v;
    };

    // ---- init (ws/LDS poisoned before every launch) ----
    {
        __half2 z2 = pkh(0.f, 0.f);
#pragma unroll 1
        for (int i = tid; i < 256 * LROW; i += 1024) lwrite(i, z2);
        __half2 e2 = __floats2half2_rn(EPSf, EPSf);
#pragma unroll 1
        for (int j = 0; j < 8; ++j) { memh2[tid + j * 1024] = e2; memW2[tid + j * 1024] = e2; }
        if (tid < 528) s_rwh[tid] = z2;
        if (tid < 32) {
            float2 xv = *(const float2*)&x[b * INd + 2 * tid];
            s_ctrlh[tid] = pkh(xv.x, xv.y);
        } else if (tid < 160) s_ctrlh[tid] = z2;
    }
    if (tid < 256) {
        s_usage[tid] = 0.f; s_ww[tid] = 0.f; s_prec[tid] = 0.f;
        s_rw[tid*4+0] = 0.f; s_rw[tid*4+1] = 0.f; s_rw[tid*4+2] = 0.f; s_rw[tid*4+3] = 0.f;
    }

#pragma unroll 1
    for (int t = 0; t < Tt; ++t) {
        __syncthreads();  // B0

        // ---- P1: GEMV1 partials ----
        {
            int kc = wv >> 2, o = (wv & 3) * 64 + lane;
            scr[kc * 256 + o] = gemv_part(wp + W1OFF + o * 4 + kc * 10240, 1024, 40,
                                          s_ctrlh + kc * 40);
        }
        __syncthreads();  // B1
        if (tid < 256) {
            float v = tanhf(b1[tid] + ((scr[tid] + scr[256+tid]) + (scr[512+tid] + scr[768+tid])));
            float pv = __shfl_xor(v, 1, 64);
            if ((tid & 1) == 0) s_hh[tid >> 1] = pkh(v, pv);
        }
        __syncthreads();  // B2

        // ---- P2: GEMV2 partials ----
        {
            int kc = wv >> 2, o = (wv & 3) * 64 + lane;
            scr[kc * 256 + o] = gemv_part(wp + W2OFF + o * 4 + kc * 8192, 1024, 32,
                                          s_hh + kc * 32);
        }
        __syncthreads();  // B3
        if (tid < 256) {
            float v = tanhf(b2[tid] + ((scr[tid] + scr[256+tid]) + (scr[512+tid] + scr[768+tid])));
            float pv = __shfl_xor(v, 1, 64);
            if ((tid & 1) == 0) s_nnh[tid >> 1] = pkh(v, pv);
        }
        __syncthreads();  // B4

        // ---- P3: GEMV3 partials ----
        {
            int kc = wv >> 3, o = (wv & 7) * 64 + lane;
            if (o < IFS)
                scr[kc * 512 + o] = gemv_part(wp + WIFOFF + o * 4 + kc * 30144, 1884, 64,
                                              s_nnh + kc * 64);
        }
        __syncthreads();  // B5
        // s_z + packed key copies.
        if (tid < IFS) {
            float v = bif[tid] + scr[tid] + scr[512 + tid];
            s_z[tid] = v;
            float pv1 = __shfl_xor(v, 1, 64);
            float pv4 = __shfl_xor(v, 4, 64);
            if (tid < 256) {
                if ((tid & 4) == 0)             // w even
                    s_keyh[(tid & 3) * 32 + (tid >> 3)] = pkh(v, pv4);
            } else if (tid >= 260 && tid < 324) {
                if ((tid & 1) == 0)
                    s_keyw2[(tid - 260) >> 1] = pkh(v, pv1);
            }
        }
        __syncthreads();  // B6

        // ---- P4: scalars + usage + wc dot/ss (merged wave roles) ----
        if (wv < 4) {
            float vz = s_z[lane * 4 + wv];
            float s = wsum(vz * vz);
            if (lane == 0) s_knorm[wv] = sqrtf(s) + EPSf;
        } else if (wv == 4) {
            float vz = s_z[260 + lane];
            float s = wsum(vz * vz);
            if (lane == 0) s_sc[3] = sqrtf(s) + EPSf;
        } else if (wv == 5) {
            if (lane < 4) s_rstr[lane] = oneplus_(s_z[256 + lane]);
            else if (lane >= 8 && lane < 12) {
                int r = lane - 8;
                float a = s_z[459+r], bm = s_z[463+r], c = s_z[467+r];
                float mx = fmaxf(a, fmaxf(bm, c));
                float ea = expf(a-mx), eb = expf(bm-mx), ec = expf(c-mx);
                float inv = 1.f / ((ea+eb)+ec);
                s_rmode[0*4+r] = ea*inv; s_rmode[1*4+r] = eb*inv; s_rmode[2*4+r] = ec*inv;
            } else if (lane == 16) s_sc[0] = oneplus_(s_z[324]);
            else if (lane == 17) s_sc[1] = sigm(s_z[457]);
            else if (lane == 18) s_sc[2] = sigm(s_z[458]);
        } else if (wv == 6) {
            s_er[lane] = sigm(s_z[325 + lane]);   // erase gates, once per step
        } else if (wv >= 8 && wv < 12) {
            int n = tid - 512;
            float ret = 1.f;
#pragma unroll
            for (int r = 0; r < 4; ++r) {
                float fg = sigm(s_z[453 + r]);
                ret *= 1.f - fg * s_rw[n*4 + r];
            }
            float u = s_usage[n], wwo = s_ww[n];
            s_usage[n] = (u + wwo - u * wwo) * ret;
        } else if (wv >= 12) {
            // wc dot/ss via memW (old mem, coalesced dword columns, pure fdot2)
            int n = tid - 768;
            const __half2* mW = memW2 + n;
            float dot = 0.f, ssv = 0.f;
#pragma unroll 1
            for (int c = 0; c < 32; c += 8) {
                __half2 mv[8], kv[8];
#pragma unroll
                for (int u = 0; u < 8; ++u) mv[u] = mW[(c + u) * 256];
                *(float4*)&kv[0] = *(const float4*)(s_keyw2 + c);
                *(float4*)&kv[4] = *(const float4*)(s_keyw2 + c + 4);
#pragma unroll
                for (int u = 0; u < 8; ++u) {
                    ssv = fdot2(mv[u], mv[u], ssv);
                    dot = fdot2(mv[u], kv[u], dot);
                }
            }
            s_wcdot[n] = dot; s_wcss[n] = ssv;
        }
        __syncthreads();  // B7

        // ---- P5: rank partials (float4 broadcast reads of usage) ----
        {
            int q = tid >> 8, n = tid & 255;
            float un = s_usage[n];
            float cnt = 0.f;
            int j0 = q * 64;
#pragma unroll 1
            for (int j = j0; j < j0 + 64; j += 4) {
                float4 uv = *(const float4*)&s_usage[j];
                cnt += (uv.x < un || (uv.x == un && j     < n)) ? 1.f : 0.f;
                cnt += (uv.y < un || (uv.y == un && j + 1 < n)) ? 1.f : 0.f;
                cnt += (uv.z < un || (uv.z == un && j + 2 < n)) ? 1.f : 0.f;
                cnt += (uv.w < un || (uv.w == un && j + 3 < n)) ? 1.f : 0.f;
            }
            scr[q * 256 + n] = cnt;
        }
        __syncthreads();  // B8

        // ---- P6: mega (wave 0) ----
        if (wv == 0) {
            int rk[4]; float uu[4];
#pragma unroll
            for (int i = 0; i < 4; ++i) {
                int n = lane * 4 + i;
                float c = scr[n] + scr[256+n] + scr[512+n] + scr[768+n];
                rk[i] = (int)(c + 0.5f);
                uu[i] = s_usage[n];
                s_srt[rk[i]] = uu[i];
            }
            float4 vs = ((const float4*)s_srt)[lane];
            float p1 = vs.x * vs.y, p2 = p1 * vs.z, tot = p2 * vs.w;
            float incl = tot;
#pragma unroll
            for (int off = 1; off < 64; off <<= 1) {
                float tv = __shfl_up(incl, off, 64);
                if (lane >= off) incl *= tv;
            }
            float excl = __shfl_up(incl, 1, 64);
            if (lane == 0) excl = 1.f;
            float4 o4v; o4v.x = excl; o4v.y = excl*vs.x; o4v.z = excl*p1; o4v.w = excl*p2;
            ((float4*)s_cp)[lane] = o4v;

            float sims[4], mx = -1e30f;
#pragma unroll
            for (int i = 0; i < 4; ++i) {
                int n = lane * 4 + i;
                sims[i] = s_wcdot[n] / ((sqrtf(s_wcss[n]) + EPSf) * s_sc[3]) * s_sc[0];
                mx = fmaxf(mx, sims[i]);
            }
            mx = wmaxr(mx);
            float es[4], ls = 0.f;
#pragma unroll
            for (int i = 0; i < 4; ++i) { es[i] = expf(sims[i] - mx); ls += es[i]; }
            ls = wsum(ls);
            float ag = s_sc[1], wg = s_sc[2], inv = 1.f / ls, lw = 0.f;
#pragma unroll
            for (int i = 0; i < 4; ++i) {
                int n = lane * 4 + i;
                float alloc = (1.f - uu[i]) * s_cp[rk[i]];
                float wwn = wg * (ag * alloc + (1.f - ag) * es[i] * inv);
                s_ww[n] = wwn; lw += wwn;
                s_wwh2[n] = pkh(wwn, wwn);                 // dup tables for pk link update
                s_tmh2[n] = pkh(1.f - wwn, 1.f - wwn);
            }
            lw = wsum(lw);
            if (lane == 0) s_red[0] = lw;
        }
        __syncthreads();  // B9

        // ---- P7: link col pass (8 waves; pk-fp16 update + perm bwd) || mem RMW (8 waves) ----
        if (tid < 512) {
            int kc = tid >> 7, p = tid & 127;
            int c0 = 2 * p, c1 = c0 + 1;
            __half2 wwcp = pkh(s_ww[c0], s_ww[c1]);
            __half2 ptp  = pkh(s_prec[c0], s_prec[c1]);
            float acc[8] = {0,0,0,0,0,0,0,0};
            int kbase = kc * 64;
#pragma unroll 1
            for (int k0 = kbase; k0 < kbase + 64; k0 += 8) {
                __half2 lv[8], tm[8], wk[8];
#pragma unroll
                for (int u = 0; u < 8; ++u) lv[u] = lread((k0 + u) * LROW + p);
                *(float4*)&tm[0] = *(const float4*)(s_tmh2 + k0);
                *(float4*)&tm[4] = *(const float4*)(s_tmh2 + k0 + 4);
                *(float4*)&wk[0] = *(const float4*)(s_wwh2 + k0);
                *(float4*)&wk[4] = *(const float4*)(s_wwh2 + k0 + 4);
                __half2 ln[8];
#pragma unroll
                for (int u = 0; u < 8; ++u)
                    ln[u] = __hfma2(__hsub2(tm[u], wwcp), lv[u], __hmul2(wk[u], ptp));
#pragma unroll
                for (int u = 0; u < 8; ++u)
                    lwrite((k0 + u) * LROW + p, ln[u]);
                int kp0 = k0 >> 1;
                __half2 l0p[4], l1p[4];
#pragma unroll
                for (int i = 0; i < 4; ++i) {
                    unsigned ua = *(unsigned*)&ln[2*i], ub = *(unsigned*)&ln[2*i+1];
                    unsigned r0 = __builtin_amdgcn_perm(ub, ua, 0x05040100u); // (.x,.x) k-pair
                    unsigned r1 = __builtin_amdgcn_perm(ub, ua, 0x07060302u); // (.y,.y) k-pair
                    l0p[i] = *(__half2*)&r0; l1p[i] = *(__half2*)&r1;
                }
#pragma unroll
                for (int r = 0; r < 4; ++r) {
                    __half2 rp[4];
                    *(float4*)rp = *(const float4*)(s_rwh + r * RWS + kp0);
#pragma unroll
                    for (int i = 0; i < 4; ++i) {
                        acc[r]     = fdot2(l0p[i], rp[i], acc[r]);
                        acc[4 + r] = fdot2(l1p[i], rp[i], acc[4 + r]);
                    }
                }
            }
            // diagonal fix: only the thread whose k-window contains rows c0,c1
            // (same 64-block since c0 even). Same-thread RAW on its own LDS words.
            if ((c0 >> 6) == kc) {
                __half2 d0 = lread(c0 * LROW + p);
                __half2 d1 = lread(c1 * LROW + p);
                float dl0 = __half2float(__low2half(d0));
                float dl1 = __half2float(__high2half(d1));
                unsigned u0 = *(unsigned*)&d0; u0 &= 0xFFFF0000u;  // zero .x (l[c0][c0])
                unsigned u1 = *(unsigned*)&d1; u1 &= 0x0000FFFFu;  // zero .y (l[c1][c1])
                lwrite(c0 * LROW + p, *(__half2*)&u0);
                lwrite(c1 * LROW + p, *(__half2*)&u1);
#pragma unroll
                for (int r = 0; r < 4; ++r) {
                    acc[r]     = fmaf(-dl0, s_rw[c0*4 + r], acc[r]);
                    acc[4 + r] = fmaf(-dl1, s_rw[c1*4 + r], acc[4 + r]);
                }
            }
            __half2* bp = (__half2*)scrh + (kc * 128 + p) * 4;
            bp[0] = pkh(acc[0], acc[1]);
            bp[1] = pkh(acc[2], acc[3]);
            bp[2] = pkh(acc[4], acc[5]);
            bp[3] = pkh(acc[6], acc[7]);
        } else {
            int t0 = tid - 512;
#pragma unroll 1
            for (int jb = 0; jb < 2; ++jb) {
                __half2 mv[8];
#pragma unroll
                for (int j = 0; j < 8; ++j) mv[j] = memh2[t0 + (jb * 8 + j) * 512];
#pragma unroll
                for (int j = 0; j < 8; ++j) {
                    int i2 = t0 + (jb * 8 + j) * 512;
                    int w = i2 >> 7, n2 = i2 & 127;
                    float er = s_er[w];
                    float wvv = s_z[389 + w];
                    float2 mf = __half22float2(mv[j]);
                    float wa = s_ww[2*n2], wb = s_ww[2*n2 + 1];
                    mf.x = mf.x * (1.f - wa * er) + wa * wvv;
                    mf.y = mf.y * (1.f - wb * er) + wb * wvv;
                    __half2 hv = __floats2half2_rn(mf.x, mf.y);
                    memh2[i2] = hv;
                    // keep w-pair copy in sync: memW[(w>>1)*256 + n] halves (w&1)
                    int wb2 = (w >> 1) * 512 + 4 * n2 + (w & 1);
                    memWh[wb2]     = __low2half(hv);    // n = 2*n2
                    memWh[wb2 + 2] = __high2half(hv);   // n = 2*n2+1
                }
            }
        }
        __syncthreads();  // B10

        // ---- P8: fwd row pass (fdot2, b128 rp broadcasts) + prec update ----
        {
            int q = tid >> 8, n8 = tid & 255;
            float f[4] = {0.f, 0.f, 0.f, 0.f};
            int base = n8 * LROW + q * 32;
#pragma unroll 1
            for (int j0 = 0; j0 < 32; j0 += 8) {
                __half2 lv[8];
#pragma unroll
                for (int u = 0; u < 8; ++u) lv[u] = lread(base + j0 + u);
#pragma unroll
                for (int r = 0; r < 4; ++r) {
                    __half2 rp[8];
                    *(float4*)&rp[0] = *(const float4*)(s_rwh + r * RWS + q * 32 + j0);
                    *(float4*)&rp[4] = *(const float4*)(s_rwh + r * RWS + q * 32 + j0 + 4);
#pragma unroll
                    for (int u = 0; u < 8; ++u) f[r] = fdot2(lv[u], rp[u], f[r]);
                }
            }
            __half2* fp2 = (__half2*)(scrh + 4096) + (q * 256 + n8) * 2;
            fp2[0] = pkh(f[0], f[1]);
            fp2[1] = pkh(f[2], f[3]);
            if (q == 0) s_prec[n8] = (1.f - s_red[0]) * s_prec[n8] + s_ww[n8];
        }
        __syncthreads();  // B11

        // ---- P9: rc sim via memW (new mem, fdot2) + bwd/fwd reduce ----
        int rr = tid >> 8, n8c = tid & 255;
        float bwv = 0.f, fwv = 0.f, e_rc = 0.f;
        {
#pragma unroll
            for (int kc = 0; kc < 4; ++kc)
                bwv += __half2float(scrh[(kc * 128 + (n8c >> 1)) * 8 + (n8c & 1) * 4 + rr]);
#pragma unroll
            for (int qq = 0; qq < 4; ++qq)
                fwv += __half2float(scrh[4096 + (qq * 256 + n8c) * 4 + rr]);
            const __half2* mW = memW2 + n8c;
            const __half2* kh = s_keyh + rr * 32;
            float ssv = 0.f, dv = 0.f;
#pragma unroll 1
            for (int c = 0; c < 32; c += 8) {
                __half2 mv[8], kv[8];
#pragma unroll
                for (int u = 0; u < 8; ++u) mv[u] = mW[(c + u) * 256];
                *(float4*)&kv[0] = *(const float4*)(kh + c);
                *(float4*)&kv[4] = *(const float4*)(kh + c + 4);
#pragma unroll
                for (int u = 0; u < 8; ++u) {
                    ssv = fdot2(mv[u], mv[u], ssv);
                    dv  = fdot2(mv[u], kv[u], dv);
                }
            }
            float sim = dv / ((sqrtf(ssv) + EPSf) * s_knorm[rr]) * s_rstr[rr];
            e_rc = expf(sim);        // |sim| small (strength-scaled cosine); R11/R13-verified
            float s = wsum(e_rc);
            if (lane == 0) s_red[16 + wv] = s;
        }
        __syncthreads();  // B12
        {
            float sm = (s_red[16+rr*4+0] + s_red[16+rr*4+1]) + (s_red[16+rr*4+2] + s_red[16+rr*4+3]);
            float rc = e_rc / sm;
            float v = bwv * s_rmode[0*4+rr] + rc * s_rmode[1*4+rr] + fwv * s_rmode[2*4+rr];
            s_rw[n8c*4 + rr] = v;
            float pv = __shfl_xor(v, 1, 64);
            if ((n8c & 1) == 0) s_rwh[rr * RWS + (n8c >> 1)] = pkh(v, pv);
        }
        __syncthreads();  // B13

        // ---- P12: rvec partials (pure fdot2: memh rows x s_rwh pairs) ----
        {
            int kc = tid >> 8, o = tid & 255, w = o >> 2, r = o & 3;
            const __half2* mw2 = (const __half2*)(memh + w * 256 + kc * 64);
            const __half2* rw2 = s_rwh + r * RWS + kc * 32;
            float a = 0.f;
#pragma unroll
            for (int c = 0; c < 8; ++c) {
                __half2 mv[4], rv[4];
                *(float4*)mv = *(const float4*)(mw2 + c * 4);
                *(float4*)rv = *(const float4*)(rw2 + c * 4);
#pragma unroll
                for (int u = 0; u < 4; ++u) a = fdot2(mv[u], rv[u], a);
            }
            scr[kc * 256 + o] = a;
        }
        __syncthreads();  // B14

        // ---- P13: rvec reduce -> ctrl pairs + next-x staging ----
        if (tid < 256) {
            float v = (scr[tid] + scr[256+tid]) + (scr[512+tid] + scr[768+tid]);
            float pv = __shfl_xor(v, 1, 64);
            if ((tid & 1) == 0) s_ctrlh[32 + (tid >> 1)] = pkh(v, pv);
        } else if (tid >= 512 && tid < 544) {
            if (t + 1 < Tt) {
                int i = tid - 512;
                float2 xv = *(const float2*)&x[((t + 1) * Bb + b) * INd + 2 * i];
                s_ctrlh[i] = pkh(xv.x, xv.y);
            }
        }
        __syncthreads();  // B15

        // ---- P14: out GEMV partials ----
        {
            int c4 = wv, o4 = lane;
            const __half2* wsrc = (c4 < 8) ? (wp + WOUTOFF + o4 * 4 + c4 * 1024)
                                           : (wp + WMEMOFF + o4 * 4 + (c4 - 8) * 1024);
            const __half2* vsrc = (c4 < 8) ? (s_nnh + c4 * 16)
                                           : (s_ctrlh + 32 + (c4 - 8) * 16);
            scr[c4 * 64 + o4] = gemv_part(wsrc, 256, 16, vsrc);
        }
        __syncthreads();  // B16
        if (tid < 64) {
            float s = 0.f;
#pragma unroll
            for (int g = 0; g < 16; ++g) s += scr[g * 64 + tid];
            out[(t * Bb + b) * OUTd + tid] = s;
        }
        // loop-top barrier covers remaining hazards
    }
}

extern "C" void kernel_launch(void* const* d_in, const int* in_sizes, int n_in,
                              void* d_out, int out_size, void* d_ws, size_t ws_size,
                              hipStream_t stream) {
    const float* x    = (const float*)d_in[0];
    const float* W1   = (const float*)d_in[1];
    const float* b1   = (const float*)d_in[2];
    const float* W2   = (const float*)d_in[3];
    const float* b2   = (const float*)d_in[4];
    const float* Wif  = (const float*)d_in[5];
    const float* bif  = (const float*)d_in[6];
    const float* Wout = (const float*)d_in[7];
    const float* Wmem = (const float*)d_in[8];
    float* out = (float*)d_out;

    // ws: [0, 601600) packed half2 weights; [601600, +512KB) mem fp16 [w][n];
    // then memW [w2][n] pair copy (512KB); then fallback link.
    char* ws = (char*)d_ws;
    __half2* wp    = (__half2*)ws;
    __half*  memg  = (__half*)(ws + 601600);
    __half2* memWg = (__half2*)(ws + 601600 + 524288);
    __half2* linkg = (__half2*)(ws + 601600 + 524288 + 524288);

    convert_weights<<<dim3((WTOT + 255) / 256), dim3(256), 0, stream>>>(W1, W2, Wif, Wout, Wmem, wp);

    hipError_t rc = hipFuncSetAttribute(
        reinterpret_cast<const void*>(&dnc_kernel<true>),
        hipFuncAttributeMaxDynamicSharedMemorySize, SMEM_MAIN);
    if (rc == hipSuccess) {
        dnc_kernel<true><<<dim3(Bb), dim3(1024), SMEM_MAIN, stream>>>(
            x, b1, b2, bif, wp, memg, memWg, linkg, out);
    } else {
        dnc_kernel<false><<<dim3(Bb), dim3(1024), SMEM_FB, stream>>>(
            x, b1, b2, bif, wp, memg, memWg, linkg, out);
    }
}

// Round 7
// 1680.133 us; speedup vs baseline: 1.7784x; 1.0931x over previous
//
#include <hip/hip_runtime.h>
#include <hip/hip_fp16.h>
#include <math.h>

#define Tt 64
#define Bb 16
#define Nn 256
#define Ww 64
#define Rr 4
#define INd 64
#define OUTd 64
#define IFS 471
#define EPSf 1e-6f

// packed half2 weight layout: quad-of-k2 per column, wave-coalesced.
#define W1OFF   0        // K2=160, Ncol=256 -> 40960
#define W2OFF   40960    // K2=128, Ncol=256 -> 32768
#define WIFOFF  73728    // K2=128, Ncol=471 -> 60288
#define WOUTOFF 134016   // K2=128, Ncol=64  -> 8192
#define WMEMOFF 142208   // K2=128, Ncol=64  -> 8192
#define WTOT    150400

// link: 256 rows x 130 dwords (even row stride -> b64 row reads in P8)
#define LROW    130
#define LINKB   (256 * LROW * 4)     // 133120 B
#define SCRB    16384                // 4096 floats / 8192 halfs
#define FIXF    3456
#define SMEM_MAIN (LINKB + SCRB + FIXF * 4)   // 163328 <= 163840
#define SMEM_FB   (SCRB + FIXF * 4)

// s_rwh padded r-stride: 132 dwords (132%32=4 -> r-groups on disjoint banks)
#define RWS 132

typedef _Float16 h2v __attribute__((ext_vector_type(2)));
__device__ __forceinline__ float fdot2(__half2 a, __half2 b, float c) {
    return __builtin_amdgcn_fdot2(*(h2v*)&a, *(h2v*)&b, c, false);
}
__device__ __forceinline__ __half2 pkh(float a, float b) {
    auto r = __builtin_amdgcn_cvt_pkrtz(a, b);   // __fp16 ext_vector(2)
    return *(__half2*)&r;
}

__device__ __forceinline__ float rcpf(float x) {
#if __has_builtin(__builtin_amdgcn_rcpf)
    return __builtin_amdgcn_rcpf(x);
#else
    return 1.f / x;
#endif
}
// fast sigmoid/tanh via native v_exp + v_rcp (~1e-6 rel err, << fp16 pipeline noise)
__device__ __forceinline__ float sigm(float x) { return rcpf(1.f + __expf(-x)); }
__device__ __forceinline__ float tanh_fast(float x) {
    float xc = fminf(fmaxf(x, -15.f), 15.f);
    float e = __expf(2.f * xc);
    return (e - 1.f) * rcpf(e + 1.f);
}
__device__ __forceinline__ float oneplus_(float x) {
    return 1.f + fmaxf(x, 0.f) + log1pf(expf(-fabsf(x)));
}
__device__ __forceinline__ float wsum(float v) {
#pragma unroll
    for (int o = 32; o; o >>= 1) v += __shfl_xor(v, o, 64);
    return v;
}
__device__ __forceinline__ float wmaxr(float v) {
#pragma unroll
    for (int o = 32; o; o >>= 1) v = fmaxf(v, __shfl_xor(v, o, 64));
    return v;
}

// shared GEMV-partial body. wP = column base (wp + OFF + n*4), str = Ncol*4
// (half2 units per k8 block), iters in k2 units (multiple of 8, >= 16).
// Weight dwordx4 loads double-buffered one chunk ahead.
__device__ __attribute__((noinline)) float gemv_part(
    const __half2* __restrict__ wP, int str, int iters,
    const __half2* __restrict__ vin)
{
    float a[8] = {0.f,0.f,0.f,0.f,0.f,0.f,0.f,0.f};
    float4 h0 = *(const float4*)(wP);
    float4 h1 = *(const float4*)(wP + str);
#pragma unroll 1
    for (int j0 = 0; j0 < iters - 8; j0 += 8) {
        int k8n = (j0 >> 2) + 2;
        float4 n0 = *(const float4*)(wP + (size_t)k8n * str);
        float4 n1 = *(const float4*)(wP + (size_t)(k8n + 1) * str);
        float4 v0 = *(const float4*)(vin + j0);
        float4 v1 = *(const float4*)(vin + j0 + 4);
        const __half2* hh0 = (const __half2*)&h0;
        const __half2* hh1 = (const __half2*)&h1;
        const __half2* vv0 = (const __half2*)&v0;
        const __half2* vv1 = (const __half2*)&v1;
#pragma unroll
        for (int u = 0; u < 4; ++u) a[u]     = fdot2(hh0[u], vv0[u], a[u]);
#pragma unroll
        for (int u = 0; u < 4; ++u) a[4 + u] = fdot2(hh1[u], vv1[u], a[4 + u]);
        h0 = n0; h1 = n1;
    }
    {
        float4 v0 = *(const float4*)(vin + iters - 8);
        float4 v1 = *(const float4*)(vin + iters - 4);
        const __half2* hh0 = (const __half2*)&h0;
        const __half2* hh1 = (const __half2*)&h1;
        const __half2* vv0 = (const __half2*)&v0;
        const __half2* vv1 = (const __half2*)&v1;
#pragma unroll
        for (int u = 0; u < 4; ++u) a[u]     = fdot2(hh0[u], vv0[u], a[u]);
#pragma unroll
        for (int u = 0; u < 4; ++u) a[4 + u] = fdot2(hh1[u], vv1[u], a[4 + u]);
    }
    return ((a[0]+a[1])+(a[2]+a[3])) + ((a[4]+a[5])+(a[6]+a[7]));
}

// ---- converter: fp32 weights -> packed half2 quad layout ----
__global__ void convert_weights(const float* __restrict__ W1, const float* __restrict__ W2,
                                const float* __restrict__ Wif, const float* __restrict__ Wout,
                                const float* __restrict__ Wmem, __half2* __restrict__ wp) {
    int i = blockIdx.x * blockDim.x + threadIdx.x;
    if (i >= WTOT) return;
    float a, b;
    if (i < W2OFF) {
        int q = i & 3, s = i >> 2, n = s & 255, k2 = (s >> 8) * 4 + q;
        a = W1[(2*k2)*256+n];  b = W1[(2*k2+1)*256+n];
    } else if (i < WIFOFF) {
        int t = i - W2OFF;
        int q = t & 3, s = t >> 2, n = s & 255, k2 = (s >> 8) * 4 + q;
        a = W2[(2*k2)*256+n];  b = W2[(2*k2+1)*256+n];
    } else if (i < WOUTOFF) {
        int t = i - WIFOFF;
        int q = t & 3, s = t >> 2, o = s % IFS, k2 = (s / IFS) * 4 + q;
        a = Wif[(2*k2)*IFS+o]; b = Wif[(2*k2+1)*IFS+o];
    } else if (i < WMEMOFF) {
        int t = i - WOUTOFF;
        int q = t & 3, s = t >> 2, n = s & 63, k2 = (s >> 6) * 4 + q;
        a = Wout[(2*k2)*64+n]; b = Wout[(2*k2+1)*64+n];
    } else {
        int t = i - WMEMOFF;
        int q = t & 3, s = t >> 2, n = s & 63, k2 = (s >> 6) * 4 + q;
        a = Wmem[(2*k2)*64+n]; b = Wmem[(2*k2+1)*64+n];
    }
    wp[i] = __floats2half2_rn(a, b);
}

template <bool LLINK>
__global__ __launch_bounds__(1024) void dnc_kernel(
    const float* __restrict__ x, const float* __restrict__ b1,
    const float* __restrict__ b2, const float* __restrict__ bif,
    const __half2* __restrict__ wp,
    __half* __restrict__ memg,      // per batch 64*256 halves, [w][n]
    __half2* __restrict__ memWg,    // per batch 32*256 dwords, [w2][n]
    __half2* __restrict__ linkg,    // fallback link
    float* __restrict__ out)
{
    extern __shared__ __align__(16) char smem[];
    const int b = blockIdx.x;
    const int tid = threadIdx.x;
    const int lane = tid & 63;
    const int wv = tid >> 6;

    __half2* l2p = (__half2*)smem;
    __half2* gl2 = linkg + (size_t)b * (256 * LROW);
    float* scr   = (float*)(smem + (LLINK ? LINKB : 0));
    __half* scrh = (__half*)scr;
    float* fx    = (float*)((char*)scr + SCRB);

    float*   s_rw    = fx + 0;                    // 1024 [n][r] fp32
    __half2* s_ctrlh = (__half2*)(fx + 1024);     // 160
    __half2* s_hh    = (__half2*)(fx + 1184);     // 128
    __half2* s_nnh   = (__half2*)(fx + 1312);     // 128
    __half2* s_rwh   = (__half2*)(fx + 1440);     // 528 = [r][RWS n-pairs]
    float* s_z     = fx + 1968;   // 472
    float* s_usage = fx + 2440;   // 256
    float* s_ww    = fx + 2696;   // 256
    float* s_prec  = fx + 2952;   // 256
    float* s_knorm = fx + 3208;   // 4
    float* s_rstr  = fx + 3212;   // 4
    float* s_rmode = fx + 3216;   // 12
    float* s_sc    = fx + 3228;   // 4
    float* s_red   = fx + 3232;   // 32 ([0]=lw, [8..12)=fg, [16..32)=rc sums)
    float* s_er    = fx + 3264;   // 64 (erase gates)
    __half2* s_keyh = (__half2*)(fx + 3328);      // 128 [r][32 w2] -> 3456 = FIXF
    float* s_srt   = scr + 1024;  // 256 (mega only, B8..B9)
    float* s_cp    = scr + 1280;  // 256 (mega only, B8..B9)
    __half2* s_keyw2 = (__half2*)(scr + 1280);    // 32 write-key pairs (B5..B7)
    float* s_wcdot = scr + 1536;  // 256 (B6..B9)
    float* s_wcss  = scr + 1792;  // 256 (B6..B9)
    __half2* s_wwh2 = (__half2*)(scr + 2048);     // 256 dup (ww,ww)   (B8..B10)
    __half2* s_tmh2 = (__half2*)(scr + 2304);     // 256 dup (1-ww,1-ww)
    unsigned* s_keyu = (unsigned*)(scr + 2560);   // 256 u64 rank keys (B6..B8)

    __half*  memh  = memg + (size_t)b * (Ww * Nn);
    __half2* memh2 = (__half2*)memh;
    __half2* memW2 = memWg + (size_t)b * (32 * 256);
    __half*  memWh = (__half*)memW2;

    auto lread = [&](int idx) -> __half2 {
        if constexpr (LLINK) return l2p[idx]; else return gl2[idx];
    };
    auto lwrite = [&](int idx, __half2 v) {
        if constexpr (LLINK) l2p[idx] = v; else gl2[idx] = v;
    };
    auto lread2 = [&](int idx) -> float2 {   // idx even: half2[idx], half2[idx+1]
        if constexpr (LLINK) return *(const float2*)(l2p + idx);
        else return *(const float2*)(gl2 + idx);
    };

    // ---- init (ws/LDS poisoned before every launch) ----
    {
        __half2 z2 = pkh(0.f, 0.f);
#pragma unroll 1
        for (int i = tid; i < 256 * LROW; i += 1024) lwrite(i, z2);
        __half2 e2 = __floats2half2_rn(EPSf, EPSf);
#pragma unroll 1
        for (int j = 0; j < 8; ++j) { memh2[tid + j * 1024] = e2; memW2[tid + j * 1024] = e2; }
        if (tid < 528) s_rwh[tid] = z2;
        if (tid < 32) {
            float2 xv = *(const float2*)&x[b * INd + 2 * tid];
            s_ctrlh[tid] = pkh(xv.x, xv.y);
        } else if (tid < 160) s_ctrlh[tid] = z2;
    }
    if (tid < 256) {
        s_usage[tid] = 0.f; s_ww[tid] = 0.f; s_prec[tid] = 0.f;
        s_rw[tid*4+0] = 0.f; s_rw[tid*4+1] = 0.f; s_rw[tid*4+2] = 0.f; s_rw[tid*4+3] = 0.f;
    }

#pragma unroll 1
    for (int t = 0; t < Tt; ++t) {
        __syncthreads();  // B0

        // ---- P1: GEMV1 partials ----
        {
            int kc = wv >> 2, o = (wv & 3) * 64 + lane;
            scr[kc * 256 + o] = gemv_part(wp + W1OFF + o * 4 + kc * 10240, 1024, 40,
                                          s_ctrlh + kc * 40);
        }
        __syncthreads();  // B1
        if (tid < 256) {
            float v = tanh_fast(b1[tid] + ((scr[tid] + scr[256+tid]) + (scr[512+tid] + scr[768+tid])));
            float pv = __shfl_xor(v, 1, 64);
            if ((tid & 1) == 0) s_hh[tid >> 1] = pkh(v, pv);
        }
        __syncthreads();  // B2

        // ---- P2: GEMV2 partials ----
        {
            int kc = wv >> 2, o = (wv & 3) * 64 + lane;
            scr[kc * 256 + o] = gemv_part(wp + W2OFF + o * 4 + kc * 8192, 1024, 32,
                                          s_hh + kc * 32);
        }
        __syncthreads();  // B3
        if (tid < 256) {
            float v = tanh_fast(b2[tid] + ((scr[tid] + scr[256+tid]) + (scr[512+tid] + scr[768+tid])));
            float pv = __shfl_xor(v, 1, 64);
            if ((tid & 1) == 0) s_nnh[tid >> 1] = pkh(v, pv);
        }
        __syncthreads();  // B4

        // ---- P3: GEMV3 partials ----
        {
            int kc = wv >> 3, o = (wv & 7) * 64 + lane;
            if (o < IFS)
                scr[kc * 512 + o] = gemv_part(wp + WIFOFF + o * 4 + kc * 30144, 1884, 64,
                                              s_nnh + kc * 64);
        }
        __syncthreads();  // B5
        // s_z + packed key copies + hoisted free-gate sigmoids
        if (tid < IFS) {
            float v = bif[tid] + scr[tid] + scr[512 + tid];
            s_z[tid] = v;
            float pv1 = __shfl_xor(v, 1, 64);
            float pv4 = __shfl_xor(v, 4, 64);
            if (tid < 256) {
                if ((tid & 4) == 0)             // w even
                    s_keyh[(tid & 3) * 32 + (tid >> 3)] = pkh(v, pv4);
            } else if (tid >= 260 && tid < 324) {
                if ((tid & 1) == 0)
                    s_keyw2[(tid - 260) >> 1] = pkh(v, pv1);
            } else if (tid >= 453 && tid < 457) {
                s_red[8 + (tid - 453)] = sigm(v);   // free gates, once
            }
        }
        __syncthreads();  // B6

        // ---- P4: scalars + usage/keys + wc dot/ss (merged wave roles) ----
        if (wv < 4) {
            float vz = s_z[lane * 4 + wv];
            float s = wsum(vz * vz);
            if (lane == 0) s_knorm[wv] = sqrtf(s) + EPSf;
        } else if (wv == 4) {
            float vz = s_z[260 + lane];
            float s = wsum(vz * vz);
            if (lane == 0) s_sc[3] = sqrtf(s) + EPSf;
        } else if (wv == 5) {
            if (lane < 4) s_rstr[lane] = oneplus_(s_z[256 + lane]);
            else if (lane >= 8 && lane < 12) {
                int r = lane - 8;
                float a = s_z[459+r], bm = s_z[463+r], c = s_z[467+r];
                float mx = fmaxf(a, fmaxf(bm, c));
                float ea = __expf(a-mx), eb = __expf(bm-mx), ec = __expf(c-mx);
                float inv = rcpf((ea+eb)+ec);
                s_rmode[0*4+r] = ea*inv; s_rmode[1*4+r] = eb*inv; s_rmode[2*4+r] = ec*inv;
            } else if (lane == 16) s_sc[0] = oneplus_(s_z[324]);
            else if (lane == 17) s_sc[1] = sigm(s_z[457]);
            else if (lane == 18) s_sc[2] = sigm(s_z[458]);
        } else if (wv == 6) {
            s_er[lane] = sigm(s_z[325 + lane]);   // erase gates, once per step
        } else if (wv >= 8 && wv < 12) {
            int n = tid - 512;
            float4 rw4 = *(const float4*)&s_rw[n*4];
            float4 fg4 = *(const float4*)&s_red[8];
            float ret = (1.f - fg4.x*rw4.x) * (1.f - fg4.y*rw4.y)
                      * (1.f - fg4.z*rw4.z) * (1.f - fg4.w*rw4.w);
            float u = s_usage[n], wwo = s_ww[n];
            float unew = (u + wwo - u * wwo) * ret;
            s_usage[n] = unew;
            // u64 sort key: usage>=0 -> IEEE bits order-monotonic; key = bits*256 + n
            unsigned ub = __float_as_uint(unew);
            s_keyu[2*n]     = (ub << 8) | (unsigned)n;
            s_keyu[2*n + 1] = ub >> 24;
        } else if (wv >= 12) {
            // wc dot/ss via memW (old mem, coalesced dword columns, batched loads)
            int n = tid - 768;
            const __half2* mW = memW2 + n;
            float dot = 0.f, ssv = 0.f;
#pragma unroll 1
            for (int hf = 0; hf < 2; ++hf) {
                __half2 mv[16], kv[16];
#pragma unroll
                for (int u = 0; u < 16; ++u) mv[u] = mW[(hf * 16 + u) * 256];
                *(float4*)&kv[0]  = *(const float4*)(s_keyw2 + hf*16);
                *(float4*)&kv[4]  = *(const float4*)(s_keyw2 + hf*16 + 4);
                *(float4*)&kv[8]  = *(const float4*)(s_keyw2 + hf*16 + 8);
                *(float4*)&kv[12] = *(const float4*)(s_keyw2 + hf*16 + 12);
#pragma unroll
                for (int u = 0; u < 16; ++u) {
                    ssv = fdot2(mv[u], mv[u], ssv);
                    dot = fdot2(mv[u], kv[u], dot);
                }
            }
            s_wcdot[n] = dot; s_wcss[n] = ssv;
        }
        __syncthreads();  // B7

        // ---- P5: rank partials (u64 keys, broadcast b128 loads) ----
        {
            int q = tid >> 8, n = tid & 255;
            unsigned long long kn = *(const unsigned long long*)&s_keyu[2*n];
            int cnt = 0;
            const unsigned long long* kp = (const unsigned long long*)s_keyu;
            int j0 = q * 64;
#pragma unroll 8
            for (int j = j0; j < j0 + 64; j += 2) {
                ulonglong2 kk = *(const ulonglong2*)&kp[j];
                cnt += (kk.x < kn);
                cnt += (kk.y < kn);
            }
            scr[q * 256 + n] = (float)cnt;
        }
        __syncthreads();  // B8

        // ---- P6: mega (wave 0) ----
        if (wv == 0) {
            int rk[4]; float uu[4];
#pragma unroll
            for (int i = 0; i < 4; ++i) {
                int n = lane * 4 + i;
                float c = scr[n] + scr[256+n] + scr[512+n] + scr[768+n];
                rk[i] = (int)(c + 0.5f);
                uu[i] = s_usage[n];
                s_srt[rk[i]] = uu[i];
            }
            float4 vs = ((const float4*)s_srt)[lane];
            float p1 = vs.x * vs.y, p2 = p1 * vs.z, tot = p2 * vs.w;
            float incl = tot;
#pragma unroll
            for (int off = 1; off < 64; off <<= 1) {
                float tv = __shfl_up(incl, off, 64);
                if (lane >= off) incl *= tv;
            }
            float excl = __shfl_up(incl, 1, 64);
            if (lane == 0) excl = 1.f;
            float4 o4v; o4v.x = excl; o4v.y = excl*vs.x; o4v.z = excl*p1; o4v.w = excl*p2;
            ((float4*)s_cp)[lane] = o4v;

            float sims[4], mx = -1e30f;
#pragma unroll
            for (int i = 0; i < 4; ++i) {
                int n = lane * 4 + i;
                sims[i] = s_wcdot[n] / ((sqrtf(s_wcss[n]) + EPSf) * s_sc[3]) * s_sc[0];
                mx = fmaxf(mx, sims[i]);
            }
            mx = wmaxr(mx);
            float es[4], ls = 0.f;
#pragma unroll
            for (int i = 0; i < 4; ++i) { es[i] = __expf(sims[i] - mx); ls += es[i]; }
            ls = wsum(ls);
            float ag = s_sc[1], wg = s_sc[2], inv = rcpf(ls), lw = 0.f;
#pragma unroll
            for (int i = 0; i < 4; ++i) {
                int n = lane * 4 + i;
                float alloc = (1.f - uu[i]) * s_cp[rk[i]];
                float wwn = wg * (ag * alloc + (1.f - ag) * es[i] * inv);
                s_ww[n] = wwn; lw += wwn;
                s_wwh2[n] = pkh(wwn, wwn);
                s_tmh2[n] = pkh(1.f - wwn, 1.f - wwn);
            }
            lw = wsum(lw);
            if (lane == 0) s_red[0] = lw;
        }
        __syncthreads();  // B9

        // ---- P7: link col pass (8 waves; pk-fp16 update + perm bwd) || mem RMW (8 waves) ----
        if (tid < 512) {
            int kc = tid >> 7, p = tid & 127;
            int c0 = 2 * p, c1 = c0 + 1;
            __half2 wwcp = pkh(s_ww[c0], s_ww[c1]);
            __half2 ptp  = pkh(s_prec[c0], s_prec[c1]);
            float acc[8] = {0,0,0,0,0,0,0,0};
            int kbase = kc * 64;
#pragma unroll 1
            for (int k0 = kbase; k0 < kbase + 64; k0 += 8) {
                __half2 lv[8], tm[8], wk[8];
#pragma unroll
                for (int u = 0; u < 8; ++u) lv[u] = lread((k0 + u) * LROW + p);
                *(float4*)&tm[0] = *(const float4*)(s_tmh2 + k0);
                *(float4*)&tm[4] = *(const float4*)(s_tmh2 + k0 + 4);
                *(float4*)&wk[0] = *(const float4*)(s_wwh2 + k0);
                *(float4*)&wk[4] = *(const float4*)(s_wwh2 + k0 + 4);
                __half2 ln[8];
#pragma unroll
                for (int u = 0; u < 8; ++u)
                    ln[u] = __hfma2(__hsub2(tm[u], wwcp), lv[u], __hmul2(wk[u], ptp));
#pragma unroll
                for (int u = 0; u < 8; ++u)
                    lwrite((k0 + u) * LROW + p, ln[u]);
                int kp0 = k0 >> 1;
                __half2 l0p[4], l1p[4];
#pragma unroll
                for (int i = 0; i < 4; ++i) {
                    unsigned ua = *(unsigned*)&ln[2*i], ub = *(unsigned*)&ln[2*i+1];
                    unsigned r0 = __builtin_amdgcn_perm(ub, ua, 0x05040100u);
                    unsigned r1 = __builtin_amdgcn_perm(ub, ua, 0x07060302u);
                    l0p[i] = *(__half2*)&r0; l1p[i] = *(__half2*)&r1;
                }
#pragma unroll
                for (int r = 0; r < 4; ++r) {
                    __half2 rp[4];
                    *(float4*)rp = *(const float4*)(s_rwh + r * RWS + kp0);
#pragma unroll
                    for (int i = 0; i < 4; ++i) {
                        acc[r]     = fdot2(l0p[i], rp[i], acc[r]);
                        acc[4 + r] = fdot2(l1p[i], rp[i], acc[4 + r]);
                    }
                }
            }
            // diagonal fix (same-thread RAW only)
            if ((c0 >> 6) == kc) {
                __half2 d0 = lread(c0 * LROW + p);
                __half2 d1 = lread(c1 * LROW + p);
                float dl0 = __half2float(__low2half(d0));
                float dl1 = __half2float(__high2half(d1));
                unsigned u0 = *(unsigned*)&d0; u0 &= 0xFFFF0000u;
                unsigned u1 = *(unsigned*)&d1; u1 &= 0x0000FFFFu;
                lwrite(c0 * LROW + p, *(__half2*)&u0);
                lwrite(c1 * LROW + p, *(__half2*)&u1);
#pragma unroll
                for (int r = 0; r < 4; ++r) {
                    acc[r]     = fmaf(-dl0, s_rw[c0*4 + r], acc[r]);
                    acc[4 + r] = fmaf(-dl1, s_rw[c1*4 + r], acc[4 + r]);
                }
            }
            __half2* bp = (__half2*)scrh + (kc * 128 + p) * 4;
            bp[0] = pkh(acc[0], acc[1]);
            bp[1] = pkh(acc[2], acc[3]);
            bp[2] = pkh(acc[4], acc[5]);
            bp[3] = pkh(acc[6], acc[7]);
        } else {
            int t0 = tid - 512;
#pragma unroll 1
            for (int jb = 0; jb < 2; ++jb) {
                __half2 mv[8];
#pragma unroll
                for (int j = 0; j < 8; ++j) mv[j] = memh2[t0 + (jb * 8 + j) * 512];
#pragma unroll
                for (int j = 0; j < 8; ++j) {
                    int i2 = t0 + (jb * 8 + j) * 512;
                    int w = i2 >> 7, n2 = i2 & 127;
                    float er = s_er[w];
                    float wvv = s_z[389 + w];
                    float2 mf = __half22float2(mv[j]);
                    float wa = s_ww[2*n2], wb = s_ww[2*n2 + 1];
                    mf.x = mf.x * (1.f - wa * er) + wa * wvv;
                    mf.y = mf.y * (1.f - wb * er) + wb * wvv;
                    __half2 hv = __floats2half2_rn(mf.x, mf.y);
                    memh2[i2] = hv;
                    int wb2 = (w >> 1) * 512 + 4 * n2 + (w & 1);
                    memWh[wb2]     = __low2half(hv);
                    memWh[wb2 + 2] = __high2half(hv);
                }
            }
        }
        __syncthreads();  // B10

        // ---- P8: fwd row pass (b64 row reads, fdot2) + prec update ----
        {
            int q = tid >> 8, n8 = tid & 255;
            float f[4] = {0.f, 0.f, 0.f, 0.f};
            int base = n8 * LROW + q * 32;   // even (LROW=130)
#pragma unroll 1
            for (int j0 = 0; j0 < 32; j0 += 8) {
                __half2 lv[8];
                float2 a0 = lread2(base + j0);
                float2 a1 = lread2(base + j0 + 2);
                float2 a2 = lread2(base + j0 + 4);
                float2 a3 = lread2(base + j0 + 6);
                *(float2*)&lv[0] = a0; *(float2*)&lv[2] = a1;
                *(float2*)&lv[4] = a2; *(float2*)&lv[6] = a3;
#pragma unroll
                for (int r = 0; r < 4; ++r) {
                    __half2 rp[8];
                    *(float4*)&rp[0] = *(const float4*)(s_rwh + r * RWS + q * 32 + j0);
                    *(float4*)&rp[4] = *(const float4*)(s_rwh + r * RWS + q * 32 + j0 + 4);
#pragma unroll
                    for (int u = 0; u < 8; ++u) f[r] = fdot2(lv[u], rp[u], f[r]);
                }
            }
            __half2* fp2 = (__half2*)(scrh + 4096) + (q * 256 + n8) * 2;
            fp2[0] = pkh(f[0], f[1]);
            fp2[1] = pkh(f[2], f[3]);
            if (q == 0) s_prec[n8] = (1.f - s_red[0]) * s_prec[n8] + s_ww[n8];
        }
        __syncthreads();  // B11

        // ---- P9: rc sim via memW (batched loads) + bwd/fwd reduce ----
        int rr = tid >> 8, n8c = tid & 255;
        float bwv = 0.f, fwv = 0.f, e_rc = 0.f;
        {
#pragma unroll
            for (int kc = 0; kc < 4; ++kc)
                bwv += __half2float(scrh[(kc * 128 + (n8c >> 1)) * 8 + (n8c & 1) * 4 + rr]);
#pragma unroll
            for (int qq = 0; qq < 4; ++qq)
                fwv += __half2float(scrh[4096 + (qq * 256 + n8c) * 4 + rr]);
            const __half2* mW = memW2 + n8c;
            const __half2* kh = s_keyh + rr * 32;
            float ssv = 0.f, dv = 0.f;
#pragma unroll 1
            for (int hf = 0; hf < 2; ++hf) {
                __half2 mv[16], kv[16];
#pragma unroll
                for (int u = 0; u < 16; ++u) mv[u] = mW[(hf * 16 + u) * 256];
                *(float4*)&kv[0]  = *(const float4*)(kh + hf*16);
                *(float4*)&kv[4]  = *(const float4*)(kh + hf*16 + 4);
                *(float4*)&kv[8]  = *(const float4*)(kh + hf*16 + 8);
                *(float4*)&kv[12] = *(const float4*)(kh + hf*16 + 12);
#pragma unroll
                for (int u = 0; u < 16; ++u) {
                    ssv = fdot2(mv[u], mv[u], ssv);
                    dv  = fdot2(mv[u], kv[u], dv);
                }
            }
            float sim = dv / ((sqrtf(ssv) + EPSf) * s_knorm[rr]) * s_rstr[rr];
            e_rc = __expf(sim);      // |sim| small (strength-scaled cosine)
            float s = wsum(e_rc);
            if (lane == 0) s_red[16 + wv] = s;
        }
        __syncthreads();  // B12
        {
            float sm = (s_red[16+rr*4+0] + s_red[16+rr*4+1]) + (s_red[16+rr*4+2] + s_red[16+rr*4+3]);
            float rc = e_rc * rcpf(sm);
            float v = bwv * s_rmode[0*4+rr] + rc * s_rmode[1*4+rr] + fwv * s_rmode[2*4+rr];
            s_rw[n8c*4 + rr] = v;
            float pv = __shfl_xor(v, 1, 64);
            if ((n8c & 1) == 0) s_rwh[rr * RWS + (n8c >> 1)] = pkh(v, pv);
        }
        __syncthreads();  // B13

        // ---- P12: rvec partials (pure fdot2: memh rows x s_rwh pairs) ----
        {
            int kc = tid >> 8, o = tid & 255, w = o >> 2, r = o & 3;
            const __half2* mw2 = (const __half2*)(memh + w * 256 + kc * 64);
            const __half2* rw2 = s_rwh + r * RWS + kc * 32;
            float a = 0.f;
#pragma unroll
            for (int c = 0; c < 8; ++c) {
                __half2 mv[4], rv[4];
                *(float4*)mv = *(const float4*)(mw2 + c * 4);
                *(float4*)rv = *(const float4*)(rw2 + c * 4);
#pragma unroll
                for (int u = 0; u < 4; ++u) a = fdot2(mv[u], rv[u], a);
            }
            scr[kc * 256 + o] = a;
        }
        __syncthreads();  // B14

        // ---- P13: rvec reduce -> ctrl pairs + next-x staging ----
        if (tid < 256) {
            float v = (scr[tid] + scr[256+tid]) + (scr[512+tid] + scr[768+tid]);
            float pv = __shfl_xor(v, 1, 64);
            if ((tid & 1) == 0) s_ctrlh[32 + (tid >> 1)] = pkh(v, pv);
        } else if (tid >= 512 && tid < 544) {
            if (t + 1 < Tt) {
                int i = tid - 512;
                float2 xv = *(const float2*)&x[((t + 1) * Bb + b) * INd + 2 * i];
                s_ctrlh[i] = pkh(xv.x, xv.y);
            }
        }
        __syncthreads();  // B15

        // ---- P14: out GEMV partials ----
        {
            int c4 = wv, o4 = lane;
            const __half2* wsrc = (c4 < 8) ? (wp + WOUTOFF + o4 * 4 + c4 * 1024)
                                           : (wp + WMEMOFF + o4 * 4 + (c4 - 8) * 1024);
            const __half2* vsrc = (c4 < 8) ? (s_nnh + c4 * 16)
                                           : (s_ctrlh + 32 + (c4 - 8) * 16);
            scr[c4 * 64 + o4] = gemv_part(wsrc, 256, 16, vsrc);
        }
        __syncthreads();  // B16
        if (tid < 64) {
            float s = 0.f;
#pragma unroll
            for (int g = 0; g < 16; ++g) s += scr[g * 64 + tid];
            out[(t * Bb + b) * OUTd + tid] = s;
        }
        // loop-top barrier covers remaining hazards
    }
}

extern "C" void kernel_launch(void* const* d_in, const int* in_sizes, int n_in,
                              void* d_out, int out_size, void* d_ws, size_t ws_size,
                              hipStream_t stream) {
    const float* x    = (const float*)d_in[0];
    const float* W1   = (const float*)d_in[1];
    const float* b1   = (const float*)d_in[2];
    const float* W2   = (const float*)d_in[3];
    const float* b2   = (const float*)d_in[4];
    const float* Wif  = (const float*)d_in[5];
    const float* bif  = (const float*)d_in[6];
    const float* Wout = (const float*)d_in[7];
    const float* Wmem = (const float*)d_in[8];
    float* out = (float*)d_out;

    // ws: [0, 601600) packed half2 weights; [601600, +512KB) mem fp16 [w][n];
    // then memW [w2][n] pair copy (512KB); then fallback link.
    char* ws = (char*)d_ws;
    __half2* wp    = (__half2*)ws;
    __half*  memg  = (__half*)(ws + 601600);
    __half2* memWg = (__half2*)(ws + 601600 + 524288);
    __half2* linkg = (__half2*)(ws + 601600 + 524288 + 524288);

    convert_weights<<<dim3((WTOT + 255) / 256), dim3(256), 0, stream>>>(W1, W2, Wif, Wout, Wmem, wp);

    hipError_t rc = hipFuncSetAttribute(
        reinterpret_cast<const void*>(&dnc_kernel<true>),
        hipFuncAttributeMaxDynamicSharedMemorySize, SMEM_MAIN);
    if (rc == hipSuccess) {
        dnc_kernel<true><<<dim3(Bb), dim3(1024), SMEM_MAIN, stream>>>(
            x, b1, b2, bif, wp, memg, memWg, linkg, out);
    } else {
        dnc_kernel<false><<<dim3(Bb), dim3(1024), SMEM_FB, stream>>>(
            x, b1, b2, bif, wp, memg, memWg, linkg, out);
    }
}

// Round 8
// 1669.233 us; speedup vs baseline: 1.7900x; 1.0065x over previous
//
#include <hip/hip_runtime.h>
#include <hip/hip_fp16.h>
#include <math.h>

#define Tt 64
#define Bb 16
#define Nn 256
#define Ww 64
#define Rr 4
#define INd 64
#define OUTd 64
#define IFS 471
#define EPSf 1e-6f

// packed half2 weight layout: quad-of-k2 per column, wave-coalesced.
#define W1OFF   0        // K2=160, Ncol=256 -> 40960
#define W2OFF   40960    // K2=128, Ncol=256 -> 32768
#define WIFOFF  73728    // K2=128, Ncol=471 -> 60288
#define WOUTOFF 134016   // K2=128, Ncol=64  -> 8192
#define WMEMOFF 142208   // K2=128, Ncol=64  -> 8192
#define WTOT    150400

// link: 256 rows x 130 dwords (even row stride -> b64 row reads in P8)
#define LROW    130
#define LINKB   (256 * LROW * 4)     // 133120 B
#define SCRB    16384                // 4096 floats / 8192 halfs
#define FIXF    3456
#define SMEM_MAIN (LINKB + SCRB + FIXF * 4)   // 163328 <= 163840
#define SMEM_FB   (SCRB + FIXF * 4)

// s_rwh padded r-stride: 132 dwords (132%32=4 -> r-groups on disjoint banks)
#define RWS 132

typedef _Float16 h2v __attribute__((ext_vector_type(2)));
__device__ __forceinline__ float fdot2(__half2 a, __half2 b, float c) {
    return __builtin_amdgcn_fdot2(*(h2v*)&a, *(h2v*)&b, c, false);
}
__device__ __forceinline__ __half2 pkh(float a, float b) {
    auto r = __builtin_amdgcn_cvt_pkrtz(a, b);   // __fp16 ext_vector(2)
    return *(__half2*)&r;
}

__device__ __forceinline__ float rcpf(float x) {
#if __has_builtin(__builtin_amdgcn_rcpf)
    return __builtin_amdgcn_rcpf(x);
#else
    return 1.f / x;
#endif
}
// fast sigmoid/tanh via native v_exp + v_rcp (~1e-6 rel err, << fp16 pipeline noise)
__device__ __forceinline__ float sigm(float x) { return rcpf(1.f + __expf(-x)); }
__device__ __forceinline__ float tanh_fast(float x) {
    float xc = fminf(fmaxf(x, -15.f), 15.f);
    float e = __expf(2.f * xc);
    return (e - 1.f) * rcpf(e + 1.f);
}
__device__ __forceinline__ float oneplus_(float x) {
    return 1.f + fmaxf(x, 0.f) + log1pf(expf(-fabsf(x)));
}
__device__ __forceinline__ float wsum(float v) {
#pragma unroll
    for (int o = 32; o; o >>= 1) v += __shfl_xor(v, o, 64);
    return v;
}
__device__ __forceinline__ float wmaxr(float v) {
#pragma unroll
    for (int o = 32; o; o >>= 1) v = fmaxf(v, __shfl_xor(v, o, 64));
    return v;
}

// shared GEMV-partial body. wP = column base (wp + OFF + n*4), str = Ncol*4
// (half2 units per k8 block), iters in k2 units (multiple of 8, >= 16).
// Weight dwordx4 loads double-buffered one chunk ahead.
__device__ __attribute__((noinline)) float gemv_part(
    const __half2* __restrict__ wP, int str, int iters,
    const __half2* __restrict__ vin)
{
    float a[8] = {0.f,0.f,0.f,0.f,0.f,0.f,0.f,0.f};
    float4 h0 = *(const float4*)(wP);
    float4 h1 = *(const float4*)(wP + str);
#pragma unroll 1
    for (int j0 = 0; j0 < iters - 8; j0 += 8) {
        int k8n = (j0 >> 2) + 2;
        float4 n0 = *(const float4*)(wP + (size_t)k8n * str);
        float4 n1 = *(const float4*)(wP + (size_t)(k8n + 1) * str);
        float4 v0 = *(const float4*)(vin + j0);
        float4 v1 = *(const float4*)(vin + j0 + 4);
        const __half2* hh0 = (const __half2*)&h0;
        const __half2* hh1 = (const __half2*)&h1;
        const __half2* vv0 = (const __half2*)&v0;
        const __half2* vv1 = (const __half2*)&v1;
#pragma unroll
        for (int u = 0; u < 4; ++u) a[u]     = fdot2(hh0[u], vv0[u], a[u]);
#pragma unroll
        for (int u = 0; u < 4; ++u) a[4 + u] = fdot2(hh1[u], vv1[u], a[4 + u]);
        h0 = n0; h1 = n1;
    }
    {
        float4 v0 = *(const float4*)(vin + iters - 8);
        float4 v1 = *(const float4*)(vin + iters - 4);
        const __half2* hh0 = (const __half2*)&h0;
        const __half2* hh1 = (const __half2*)&h1;
        const __half2* vv0 = (const __half2*)&v0;
        const __half2* vv1 = (const __half2*)&v1;
#pragma unroll
        for (int u = 0; u < 4; ++u) a[u]     = fdot2(hh0[u], vv0[u], a[u]);
#pragma unroll
        for (int u = 0; u < 4; ++u) a[4 + u] = fdot2(hh1[u], vv1[u], a[4 + u]);
    }
    return ((a[0]+a[1])+(a[2]+a[3])) + ((a[4]+a[5])+(a[6]+a[7]));
}

// ---- converter: fp32 weights -> packed half2 quad layout ----
__global__ void convert_weights(const float* __restrict__ W1, const float* __restrict__ W2,
                                const float* __restrict__ Wif, const float* __restrict__ Wout,
                                const float* __restrict__ Wmem, __half2* __restrict__ wp) {
    int i = blockIdx.x * blockDim.x + threadIdx.x;
    if (i >= WTOT) return;
    float a, b;
    if (i < W2OFF) {
        int q = i & 3, s = i >> 2, n = s & 255, k2 = (s >> 8) * 4 + q;
        a = W1[(2*k2)*256+n];  b = W1[(2*k2+1)*256+n];
    } else if (i < WIFOFF) {
        int t = i - W2OFF;
        int q = t & 3, s = t >> 2, n = s & 255, k2 = (s >> 8) * 4 + q;
        a = W2[(2*k2)*256+n];  b = W2[(2*k2+1)*256+n];
    } else if (i < WOUTOFF) {
        int t = i - WIFOFF;
        int q = t & 3, s = t >> 2, o = s % IFS, k2 = (s / IFS) * 4 + q;
        a = Wif[(2*k2)*IFS+o]; b = Wif[(2*k2+1)*IFS+o];
    } else if (i < WMEMOFF) {
        int t = i - WOUTOFF;
        int q = t & 3, s = t >> 2, n = s & 63, k2 = (s >> 6) * 4 + q;
        a = Wout[(2*k2)*64+n]; b = Wout[(2*k2+1)*64+n];
    } else {
        int t = i - WMEMOFF;
        int q = t & 3, s = t >> 2, n = s & 63, k2 = (s >> 6) * 4 + q;
        a = Wmem[(2*k2)*64+n]; b = Wmem[(2*k2+1)*64+n];
    }
    wp[i] = __floats2half2_rn(a, b);
}

template <bool LLINK>
__global__ __launch_bounds__(1024) void dnc_kernel(
    const float* __restrict__ x, const float* __restrict__ b1,
    const float* __restrict__ b2, const float* __restrict__ bif,
    const __half2* __restrict__ wp,
    __half* __restrict__ memg,      // per batch 64*256 halves, [w][n]
    __half2* __restrict__ memWg,    // per batch 32*256 dwords, [w2][n]
    __half2* __restrict__ linkg,    // fallback link
    float* __restrict__ out)
{
    extern __shared__ __align__(16) char smem[];
    const int b = blockIdx.x;
    const int tid = threadIdx.x;
    const int lane = tid & 63;
    const int wv = tid >> 6;

    __half2* l2p = (__half2*)smem;
    __half2* gl2 = linkg + (size_t)b * (256 * LROW);
    float* scr   = (float*)(smem + (LLINK ? LINKB : 0));
    __half* scrh = (__half*)scr;
    float* fx    = (float*)((char*)scr + SCRB);

    float*   s_rw    = fx + 0;                    // 1024 [n][r] fp32
    __half2* s_ctrlh = (__half2*)(fx + 1024);     // 160
    __half2* s_hh    = (__half2*)(fx + 1184);     // 128
    __half2* s_nnh   = (__half2*)(fx + 1312);     // 128
    __half2* s_rwh   = (__half2*)(fx + 1440);     // 528 = [r][RWS n-pairs]
    float* s_z     = fx + 1968;   // 472
    float* s_usage = fx + 2440;   // 256
    float* s_ww    = fx + 2696;   // 256
    float* s_prec  = fx + 2952;   // 256
    float* s_knorm = fx + 3208;   // 4
    float* s_rstr  = fx + 3212;   // 4
    float* s_rmode = fx + 3216;   // 12
    float* s_sc    = fx + 3228;   // 4
    float* s_red   = fx + 3232;   // 32 ([0]=lw, [8..12)=fg, [16..32)=rc sums)
    float* s_er    = fx + 3264;   // 64 (erase gates)
    __half2* s_keyh = (__half2*)(fx + 3328);      // 128 [r][32 w2] -> 3456 = FIXF
    float* s_srt   = scr + 1024;  // 256 (mega only, B8..B9)
    float* s_cp    = scr + 1280;  // 256 (mega only, B8..B9)
    __half2* s_keyw2 = (__half2*)(scr + 1280);    // 32 write-key pairs (B6..B7)
    float* s_wcdot = scr + 1536;  // 256 (B7..B9)
    float* s_wcss  = scr + 1792;  // 256 (B7..B9)
    __half2* s_wwh2 = (__half2*)(scr + 2048);     // 256 dup (ww,ww)   (B9..B10)
    __half2* s_tmh2 = (__half2*)(scr + 2304);     // 256 dup (1-ww,1-ww)
    unsigned* s_keyu = (unsigned*)(scr + 2560);   // 256 u64 rank keys (B7..B8)

    __half*  memh  = memg + (size_t)b * (Ww * Nn);
    __half2* memh2 = (__half2*)memh;
    __half2* memW2 = memWg + (size_t)b * (32 * 256);
    __half*  memWh = (__half*)memW2;

    auto lread = [&](int idx) -> __half2 {
        if constexpr (LLINK) return l2p[idx]; else return gl2[idx];
    };
    auto lwrite = [&](int idx, __half2 v) {
        if constexpr (LLINK) l2p[idx] = v; else gl2[idx] = v;
    };
    auto lread2 = [&](int idx) -> float2 {   // idx even: half2[idx], half2[idx+1]
        if constexpr (LLINK) return *(const float2*)(l2p + idx);
        else return *(const float2*)(gl2 + idx);
    };

    // ---- init (ws/LDS poisoned before every launch) ----
    {
        __half2 z2 = pkh(0.f, 0.f);
#pragma unroll 1
        for (int i = tid; i < 256 * LROW; i += 1024) lwrite(i, z2);
        __half2 e2 = __floats2half2_rn(EPSf, EPSf);
#pragma unroll 1
        for (int j = 0; j < 8; ++j) { memh2[tid + j * 1024] = e2; memW2[tid + j * 1024] = e2; }
        if (tid < 528) s_rwh[tid] = z2;
        if (tid < 32) {
            float2 xv = *(const float2*)&x[b * INd + 2 * tid];
            s_ctrlh[tid] = pkh(xv.x, xv.y);
        } else if (tid < 160) s_ctrlh[tid] = z2;
    }
    if (tid < 256) {
        s_usage[tid] = 0.f; s_ww[tid] = 0.f; s_prec[tid] = 0.f;
        s_rw[tid*4+0] = 0.f; s_rw[tid*4+1] = 0.f; s_rw[tid*4+2] = 0.f; s_rw[tid*4+3] = 0.f;
    }
    __syncthreads();   // entry barrier (loop-top barrier removed)

#pragma unroll 1
    for (int t = 0; t < Tt; ++t) {
        // ---- P1: GEMV1, in-wave reduce + tanh -> s_hh ----
        {
            int o = (wv << 4) + (lane & 15), kc = lane >> 4;
            float a = gemv_part(wp + W1OFF + o * 4 + kc * 10240, 1024, 40,
                                s_ctrlh + kc * 40);
            a += __shfl_xor(a, 16, 64);
            a += __shfl_xor(a, 32, 64);
            if (lane < 16) {
                float v = tanh_fast(b1[o] + a);
                float pv = __shfl_xor(v, 1, 64);
                if ((lane & 1) == 0) s_hh[o >> 1] = pkh(v, pv);
            }
        }
        __syncthreads();  // B2

        // ---- P2: GEMV2, in-wave reduce + tanh -> s_nnh ----
        {
            int o = (wv << 4) + (lane & 15), kc = lane >> 4;
            float a = gemv_part(wp + W2OFF + o * 4 + kc * 8192, 1024, 32,
                                s_hh + kc * 32);
            a += __shfl_xor(a, 16, 64);
            a += __shfl_xor(a, 32, 64);
            if (lane < 16) {
                float v = tanh_fast(b2[o] + a);
                float pv = __shfl_xor(v, 1, 64);
                if ((lane & 1) == 0) s_nnh[o >> 1] = pkh(v, pv);
            }
        }
        __syncthreads();  // B4

        // ---- P3: GEMV3, in-wave reduce -> s_z + packed keys + free gates ----
        {
            int o = (wv << 5) + (lane & 31);
            int kc = lane >> 5;
            float a = 0.f;
            if (o < IFS)
                a = gemv_part(wp + WIFOFF + o * 4 + kc * 30144, 1884, 64,
                              s_nnh + kc * 64);
            a += __shfl_xor(a, 32, 64);
            if (lane < 32 && o < IFS) {
                float v = bif[o] + a;
                s_z[o] = v;
                float pv1 = __shfl_xor(v, 1, 64);
                float pv4 = __shfl_xor(v, 4, 64);
                if (o < 256) {
                    if ((o & 4) == 0)           // w even
                        s_keyh[(o & 3) * 32 + (o >> 3)] = pkh(v, pv4);
                } else if (o >= 260 && o < 324) {
                    if ((o & 1) == 0)
                        s_keyw2[(o - 260) >> 1] = pkh(v, pv1);
                } else if (o >= 453 && o < 457) {
                    s_red[8 + (o - 453)] = sigm(v);   // free gates, once
                }
            }
        }
        __syncthreads();  // B6

        // ---- P4: scalars + usage/keys + wc dot/ss (merged wave roles) ----
        if (wv < 4) {
            float vz = s_z[lane * 4 + wv];
            float s = wsum(vz * vz);
            if (lane == 0) s_knorm[wv] = sqrtf(s) + EPSf;
        } else if (wv == 4) {
            float vz = s_z[260 + lane];
            float s = wsum(vz * vz);
            if (lane == 0) s_sc[3] = sqrtf(s) + EPSf;
        } else if (wv == 5) {
            if (lane < 4) s_rstr[lane] = oneplus_(s_z[256 + lane]);
            else if (lane >= 8 && lane < 12) {
                int r = lane - 8;
                float a = s_z[459+r], bm = s_z[463+r], c = s_z[467+r];
                float mx = fmaxf(a, fmaxf(bm, c));
                float ea = __expf(a-mx), eb = __expf(bm-mx), ec = __expf(c-mx);
                float inv = rcpf((ea+eb)+ec);
                s_rmode[0*4+r] = ea*inv; s_rmode[1*4+r] = eb*inv; s_rmode[2*4+r] = ec*inv;
            } else if (lane == 16) s_sc[0] = oneplus_(s_z[324]);
            else if (lane == 17) s_sc[1] = sigm(s_z[457]);
            else if (lane == 18) s_sc[2] = sigm(s_z[458]);
        } else if (wv == 6) {
            s_er[lane] = sigm(s_z[325 + lane]);   // erase gates, once per step
        } else if (wv >= 8 && wv < 12) {
            int n = tid - 512;
            float4 rw4 = *(const float4*)&s_rw[n*4];
            float4 fg4 = *(const float4*)&s_red[8];
            float ret = (1.f - fg4.x*rw4.x) * (1.f - fg4.y*rw4.y)
                      * (1.f - fg4.z*rw4.z) * (1.f - fg4.w*rw4.w);
            float u = s_usage[n], wwo = s_ww[n];
            float unew = (u + wwo - u * wwo) * ret;
            s_usage[n] = unew;
            // u64 sort key: usage>=0 -> IEEE bits order-monotonic; key = bits*256 + n
            unsigned ub = __float_as_uint(unew);
            s_keyu[2*n]     = (ub << 8) | (unsigned)n;
            s_keyu[2*n + 1] = ub >> 24;
        } else if (wv >= 12) {
            // wc dot/ss via memW (old mem, coalesced dword columns, batched loads)
            int n = tid - 768;
            const __half2* mW = memW2 + n;
            float dot = 0.f, ssv = 0.f;
#pragma unroll 1
            for (int hf = 0; hf < 2; ++hf) {
                __half2 mv[16], kv[16];
#pragma unroll
                for (int u = 0; u < 16; ++u) mv[u] = mW[(hf * 16 + u) * 256];
                *(float4*)&kv[0]  = *(const float4*)(s_keyw2 + hf*16);
                *(float4*)&kv[4]  = *(const float4*)(s_keyw2 + hf*16 + 4);
                *(float4*)&kv[8]  = *(const float4*)(s_keyw2 + hf*16 + 8);
                *(float4*)&kv[12] = *(const float4*)(s_keyw2 + hf*16 + 12);
#pragma unroll
                for (int u = 0; u < 16; ++u) {
                    ssv = fdot2(mv[u], mv[u], ssv);
                    dot = fdot2(mv[u], kv[u], dot);
                }
            }
            s_wcdot[n] = dot; s_wcss[n] = ssv;
        }
        __syncthreads();  // B7

        // ---- P5: rank partials (u64 keys, broadcast b128 loads) ----
        {
            int q = tid >> 8, n = tid & 255;
            unsigned long long kn = *(const unsigned long long*)&s_keyu[2*n];
            int cnt = 0;
            const unsigned long long* kp = (const unsigned long long*)s_keyu;
            int j0 = q * 64;
#pragma unroll 8
            for (int j = j0; j < j0 + 64; j += 2) {
                ulonglong2 kk = *(const ulonglong2*)&kp[j];
                cnt += (kk.x < kn);
                cnt += (kk.y < kn);
            }
            scr[q * 256 + n] = (float)cnt;
        }
        __syncthreads();  // B8

        // ---- P6: mega (wave 0) ----
        if (wv == 0) {
            int rk[4]; float uu[4];
#pragma unroll
            for (int i = 0; i < 4; ++i) {
                int n = lane * 4 + i;
                float c = scr[n] + scr[256+n] + scr[512+n] + scr[768+n];
                rk[i] = (int)(c + 0.5f);
                uu[i] = s_usage[n];
                s_srt[rk[i]] = uu[i];
            }
            float4 vs = ((const float4*)s_srt)[lane];
            float p1 = vs.x * vs.y, p2 = p1 * vs.z, tot = p2 * vs.w;
            float incl = tot;
#pragma unroll
            for (int off = 1; off < 64; off <<= 1) {
                float tv = __shfl_up(incl, off, 64);
                if (lane >= off) incl *= tv;
            }
            float excl = __shfl_up(incl, 1, 64);
            if (lane == 0) excl = 1.f;
            float4 o4v; o4v.x = excl; o4v.y = excl*vs.x; o4v.z = excl*p1; o4v.w = excl*p2;
            ((float4*)s_cp)[lane] = o4v;

            float sims[4], mx = -1e30f;
#pragma unroll
            for (int i = 0; i < 4; ++i) {
                int n = lane * 4 + i;
                sims[i] = s_wcdot[n] / ((sqrtf(s_wcss[n]) + EPSf) * s_sc[3]) * s_sc[0];
                mx = fmaxf(mx, sims[i]);
            }
            mx = wmaxr(mx);
            float es[4], ls = 0.f;
#pragma unroll
            for (int i = 0; i < 4; ++i) { es[i] = __expf(sims[i] - mx); ls += es[i]; }
            ls = wsum(ls);
            float ag = s_sc[1], wg = s_sc[2], inv = rcpf(ls), lw = 0.f;
#pragma unroll
            for (int i = 0; i < 4; ++i) {
                int n = lane * 4 + i;
                float alloc = (1.f - uu[i]) * s_cp[rk[i]];
                float wwn = wg * (ag * alloc + (1.f - ag) * es[i] * inv);
                s_ww[n] = wwn; lw += wwn;
                s_wwh2[n] = pkh(wwn, wwn);
                s_tmh2[n] = pkh(1.f - wwn, 1.f - wwn);
            }
            lw = wsum(lw);
            if (lane == 0) s_red[0] = lw;
        }
        __syncthreads();  // B9

        // ---- P7: link col pass (8 waves; pk-fp16 update + perm bwd) || mem RMW (8 waves) ----
        if (tid < 512) {
            int kc = tid >> 7, p = tid & 127;
            int c0 = 2 * p, c1 = c0 + 1;
            __half2 wwcp = pkh(s_ww[c0], s_ww[c1]);
            __half2 ptp  = pkh(s_prec[c0], s_prec[c1]);
            float acc[8] = {0,0,0,0,0,0,0,0};
            int kbase = kc * 64;
#pragma unroll 1
            for (int k0 = kbase; k0 < kbase + 64; k0 += 8) {
                __half2 lv[8], tm[8], wk[8];
#pragma unroll
                for (int u = 0; u < 8; ++u) lv[u] = lread((k0 + u) * LROW + p);
                *(float4*)&tm[0] = *(const float4*)(s_tmh2 + k0);
                *(float4*)&tm[4] = *(const float4*)(s_tmh2 + k0 + 4);
                *(float4*)&wk[0] = *(const float4*)(s_wwh2 + k0);
                *(float4*)&wk[4] = *(const float4*)(s_wwh2 + k0 + 4);
                __half2 ln[8];
#pragma unroll
                for (int u = 0; u < 8; ++u)
                    ln[u] = __hfma2(__hsub2(tm[u], wwcp), lv[u], __hmul2(wk[u], ptp));
#pragma unroll
                for (int u = 0; u < 8; ++u)
                    lwrite((k0 + u) * LROW + p, ln[u]);
                int kp0 = k0 >> 1;
                __half2 l0p[4], l1p[4];
#pragma unroll
                for (int i = 0; i < 4; ++i) {
                    unsigned ua = *(unsigned*)&ln[2*i], ub = *(unsigned*)&ln[2*i+1];
                    unsigned r0 = __builtin_amdgcn_perm(ub, ua, 0x05040100u);
                    unsigned r1 = __builtin_amdgcn_perm(ub, ua, 0x07060302u);
                    l0p[i] = *(__half2*)&r0; l1p[i] = *(__half2*)&r1;
                }
#pragma unroll
                for (int r = 0; r < 4; ++r) {
                    __half2 rp[4];
                    *(float4*)rp = *(const float4*)(s_rwh + r * RWS + kp0);
#pragma unroll
                    for (int i = 0; i < 4; ++i) {
                        acc[r]     = fdot2(l0p[i], rp[i], acc[r]);
                        acc[4 + r] = fdot2(l1p[i], rp[i], acc[4 + r]);
                    }
                }
            }
            // diagonal fix (same-thread RAW only)
            if ((c0 >> 6) == kc) {
                __half2 d0 = lread(c0 * LROW + p);
                __half2 d1 = lread(c1 * LROW + p);
                float dl0 = __half2float(__low2half(d0));
                float dl1 = __half2float(__high2half(d1));
                unsigned u0 = *(unsigned*)&d0; u0 &= 0xFFFF0000u;
                unsigned u1 = *(unsigned*)&d1; u1 &= 0x0000FFFFu;
                lwrite(c0 * LROW + p, *(__half2*)&u0);
                lwrite(c1 * LROW + p, *(__half2*)&u1);
#pragma unroll
                for (int r = 0; r < 4; ++r) {
                    acc[r]     = fmaf(-dl0, s_rw[c0*4 + r], acc[r]);
                    acc[4 + r] = fmaf(-dl1, s_rw[c1*4 + r], acc[4 + r]);
                }
            }
            __half2* bp = (__half2*)scrh + (kc * 128 + p) * 4;
            bp[0] = pkh(acc[0], acc[1]);
            bp[1] = pkh(acc[2], acc[3]);
            bp[2] = pkh(acc[4], acc[5]);
            bp[3] = pkh(acc[6], acc[7]);
        } else {
            int t0 = tid - 512;
#pragma unroll 1
            for (int jb = 0; jb < 2; ++jb) {
                __half2 mv[8];
#pragma unroll
                for (int j = 0; j < 8; ++j) mv[j] = memh2[t0 + (jb * 8 + j) * 512];
#pragma unroll
                for (int j = 0; j < 8; ++j) {
                    int i2 = t0 + (jb * 8 + j) * 512;
                    int w = i2 >> 7, n2 = i2 & 127;
                    float er = s_er[w];
                    float wvv = s_z[389 + w];
                    float2 mf = __half22float2(mv[j]);
                    float wa = s_ww[2*n2], wb = s_ww[2*n2 + 1];
                    mf.x = mf.x * (1.f - wa * er) + wa * wvv;
                    mf.y = mf.y * (1.f - wb * er) + wb * wvv;
                    __half2 hv = __floats2half2_rn(mf.x, mf.y);
                    memh2[i2] = hv;
                    int wb2 = (w >> 1) * 512 + 4 * n2 + (w & 1);
                    memWh[wb2]     = __low2half(hv);
                    memWh[wb2 + 2] = __high2half(hv);
                }
            }
        }
        __syncthreads();  // B10

        // ---- P8: fwd row pass (b64 row reads, fdot2) + prec update ----
        {
            int q = tid >> 8, n8 = tid & 255;
            float f[4] = {0.f, 0.f, 0.f, 0.f};
            int base = n8 * LROW + q * 32;   // even (LROW=130)
#pragma unroll 1
            for (int j0 = 0; j0 < 32; j0 += 8) {
                __half2 lv[8];
                float2 a0 = lread2(base + j0);
                float2 a1 = lread2(base + j0 + 2);
                float2 a2 = lread2(base + j0 + 4);
                float2 a3 = lread2(base + j0 + 6);
                *(float2*)&lv[0] = a0; *(float2*)&lv[2] = a1;
                *(float2*)&lv[4] = a2; *(float2*)&lv[6] = a3;
#pragma unroll
                for (int r = 0; r < 4; ++r) {
                    __half2 rp[8];
                    *(float4*)&rp[0] = *(const float4*)(s_rwh + r * RWS + q * 32 + j0);
                    *(float4*)&rp[4] = *(const float4*)(s_rwh + r * RWS + q * 32 + j0 + 4);
#pragma unroll
                    for (int u = 0; u < 8; ++u) f[r] = fdot2(lv[u], rp[u], f[r]);
                }
            }
            __half2* fp2 = (__half2*)(scrh + 4096) + (q * 256 + n8) * 2;
            fp2[0] = pkh(f[0], f[1]);
            fp2[1] = pkh(f[2], f[3]);
            if (q == 0) s_prec[n8] = (1.f - s_red[0]) * s_prec[n8] + s_ww[n8];
        }
        __syncthreads();  // B11

        // ---- P9: rc sim via memW (batched loads) + bwd/fwd reduce ----
        int rr = tid >> 8, n8c = tid & 255;
        float bwv = 0.f, fwv = 0.f, e_rc = 0.f;
        {
#pragma unroll
            for (int kc = 0; kc < 4; ++kc)
                bwv += __half2float(scrh[(kc * 128 + (n8c >> 1)) * 8 + (n8c & 1) * 4 + rr]);
#pragma unroll
            for (int qq = 0; qq < 4; ++qq)
                fwv += __half2float(scrh[4096 + (qq * 256 + n8c) * 4 + rr]);
            const __half2* mW = memW2 + n8c;
            const __half2* kh = s_keyh + rr * 32;
            float ssv = 0.f, dv = 0.f;
#pragma unroll 1
            for (int hf = 0; hf < 2; ++hf) {
                __half2 mv[16], kv[16];
#pragma unroll
                for (int u = 0; u < 16; ++u) mv[u] = mW[(hf * 16 + u) * 256];
                *(float4*)&kv[0]  = *(const float4*)(kh + hf*16);
                *(float4*)&kv[4]  = *(const float4*)(kh + hf*16 + 4);
                *(float4*)&kv[8]  = *(const float4*)(kh + hf*16 + 8);
                *(float4*)&kv[12] = *(const float4*)(kh + hf*16 + 12);
#pragma unroll
                for (int u = 0; u < 16; ++u) {
                    ssv = fdot2(mv[u], mv[u], ssv);
                    dv  = fdot2(mv[u], kv[u], dv);
                }
            }
            float sim = dv / ((sqrtf(ssv) + EPSf) * s_knorm[rr]) * s_rstr[rr];
            e_rc = __expf(sim);      // |sim| small (strength-scaled cosine)
            float s = wsum(e_rc);
            if (lane == 0) s_red[16 + wv] = s;
        }
        __syncthreads();  // B12
        {
            float sm = (s_red[16+rr*4+0] + s_red[16+rr*4+1]) + (s_red[16+rr*4+2] + s_red[16+rr*4+3]);
            float rc = e_rc * rcpf(sm);
            float v = bwv * s_rmode[0*4+rr] + rc * s_rmode[1*4+rr] + fwv * s_rmode[2*4+rr];
            s_rw[n8c*4 + rr] = v;
            float pv = __shfl_xor(v, 1, 64);
            if ((n8c & 1) == 0) s_rwh[rr * RWS + (n8c >> 1)] = pkh(v, pv);
        }
        __syncthreads();  // B13

        // ---- P12: rvec, in-wave reduce -> ctrl pairs + next-x staging ----
        {
            int o = (wv << 4) + (lane & 15), kc = lane >> 4;
            int w = o >> 2, r = o & 3;
            const __half2* mw2 = (const __half2*)(memh + w * 256 + kc * 64);
            const __half2* rw2 = s_rwh + r * RWS + kc * 32;
            float a = 0.f;
#pragma unroll
            for (int c = 0; c < 8; ++c) {
                __half2 mv[4], rv[4];
                *(float4*)mv = *(const float4*)(mw2 + c * 4);
                *(float4*)rv = *(const float4*)(rw2 + c * 4);
#pragma unroll
                for (int u = 0; u < 4; ++u) a = fdot2(mv[u], rv[u], a);
            }
            a += __shfl_xor(a, 16, 64);
            a += __shfl_xor(a, 32, 64);
            if (lane < 16) {
                float pv = __shfl_xor(a, 1, 64);
                if ((lane & 1) == 0) s_ctrlh[32 + (o >> 1)] = pkh(a, pv);
            }
            if (wv < 2 && lane >= 48 && t + 1 < Tt) {
                int i = (wv << 4) + (lane - 48);
                float2 xv = *(const float2*)&x[((t + 1) * Bb + b) * INd + 2 * i];
                s_ctrlh[i] = pkh(xv.x, xv.y);
            }
        }
        __syncthreads();  // B15

        // ---- P14: out GEMV, in-wave 16-lane reduce -> direct global write ----
        {
            int o = (wv << 2) + (lane & 3), c = lane >> 2;
            const __half2* wsrc = (c < 8) ? (wp + WOUTOFF + o * 4 + c * 1024)
                                          : (wp + WMEMOFF + o * 4 + (c - 8) * 1024);
            const __half2* vsrc = (c < 8) ? (s_nnh + c * 16)
                                          : (s_ctrlh + 32 + (c - 8) * 16);
            float a = gemv_part(wsrc, 256, 16, vsrc);
            a += __shfl_xor(a, 4, 64);
            a += __shfl_xor(a, 8, 64);
            a += __shfl_xor(a, 16, 64);
            a += __shfl_xor(a, 32, 64);
            if (lane < 4) out[(t * Bb + b) * OUTd + o] = a;
        }
        // no loop-top barrier: P14 reads s_nnh/ctrl[32..) only; next P1 writes s_hh
        // (disjoint); ctrl stable since B15. First-iteration covered by entry barrier.
    }
}

extern "C" void kernel_launch(void* const* d_in, const int* in_sizes, int n_in,
                              void* d_out, int out_size, void* d_ws, size_t ws_size,
                              hipStream_t stream) {
    const float* x    = (const float*)d_in[0];
    const float* W1   = (const float*)d_in[1];
    const float* b1   = (const float*)d_in[2];
    const float* W2   = (const float*)d_in[3];
    const float* b2   = (const float*)d_in[4];
    const float* Wif  = (const float*)d_in[5];
    const float* bif  = (const float*)d_in[6];
    const float* Wout = (const float*)d_in[7];
    const float* Wmem = (const float*)d_in[8];
    float* out = (float*)d_out;

    // ws: [0, 601600) packed half2 weights; [601600, +512KB) mem fp16 [w][n];
    // then memW [w2][n] pair copy (512KB); then fallback link.
    char* ws = (char*)d_ws;
    __half2* wp    = (__half2*)ws;
    __half*  memg  = (__half*)(ws + 601600);
    __half2* memWg = (__half2*)(ws + 601600 + 524288);
    __half2* linkg = (__half2*)(ws + 601600 + 524288 + 524288);

    convert_weights<<<dim3((WTOT + 255) / 256), dim3(256), 0, stream>>>(W1, W2, Wif, Wout, Wmem, wp);

    hipError_t rc = hipFuncSetAttribute(
        reinterpret_cast<const void*>(&dnc_kernel<true>),
        hipFuncAttributeMaxDynamicSharedMemorySize, SMEM_MAIN);
    if (rc == hipSuccess) {
        dnc_kernel<true><<<dim3(Bb), dim3(1024), SMEM_MAIN, stream>>>(
            x, b1, b2, bif, wp, memg, memWg, linkg, out);
    } else {
        dnc_kernel<false><<<dim3(Bb), dim3(1024), SMEM_FB, stream>>>(
            x, b1, b2, bif, wp, memg, memWg, linkg, out);
    }
}